// Round 16
// baseline (566.475 us; speedup 1.0000x reference)
//
#include <hip/hip_runtime.h>

#define TPB 256

typedef __attribute__((ext_vector_type(4))) float v4f;
typedef __attribute__((ext_vector_type(8))) short v8s;

__device__ __forceinline__ float us2f(unsigned int u) {
    union { unsigned int i; float f; } w; w.i = u << 16; return w.f;
}
__device__ __forceinline__ unsigned short f2us(float f) {
    union { float ff; unsigned int i; } w; w.ff = f;
    unsigned int u = w.i;
    return (unsigned short)((u + 0x7fffu + ((u >> 16) & 1u)) >> 16);
}
// Async global->LDS DMA, 16 B per lane. LDS dest = wave-uniform base + lane*16.
// NOTE: the GLOBAL source is PER-LANE — each lane loads 16 B from its own g.
__device__ __forceinline__ void gl_lds16(const unsigned short* g, unsigned short* l) {
    __builtin_amdgcn_global_load_lds(
        (const __attribute__((address_space(1))) unsigned int*)g,
        (__attribute__((address_space(3))) unsigned int*)l, 16, 0, 0);
}

// ---------------------------------------------------------------------------
// MERGED weight repack: all 8 repacks + zpage zeroing in ONE kernel.
// ---------------------------------------------------------------------------
__global__ __launch_bounds__(TPB) void repack_all(
    const float* __restrict__ e_w1, const float* __restrict__ d_w4,
    const float* __restrict__ e_w2, const float* __restrict__ e_w3,
    const float* __restrict__ e_w4, const float* __restrict__ d_w1,
    const float* __restrict__ d_w2, const float* __restrict__ d_w3,
    unsigned short* __restrict__ we1, unsigned short* __restrict__ wd4r,
    unsigned short* __restrict__ we2, unsigned short* __restrict__ we3,
    unsigned short* __restrict__ we4, unsigned short* __restrict__ wd1,
    unsigned short* __restrict__ wd2, unsigned short* __restrict__ wd3,
    unsigned short* __restrict__ zpage)
{
    int gid = blockIdx.x * TPB + threadIdx.x;
    if (gid < 2048) {
        int idx = gid;
        int k = idx & 31, co = idx >> 5;
        we1[idx] = (k < 27) ? f2us(e_w1[co * 27 + k]) : (unsigned short)0;
        return;
    }
    gid -= 2048;
    if (gid < 9216) {
        int idx = gid;
        int e = idx & 7;
        int lane = (idx >> 3) & 63;
        int kk = idx >> 9;
        int lr = lane & 15, lc = lane >> 4;
        int tap = kk >> 1, half = kk & 1;
        int ci = half * 32 + lc * 8 + e;
        wd4r[idx] = (lr < 3) ? f2us(d_w4[((size_t)lr * 64 + ci) * 9 + tap])
                             : (unsigned short)0;
        return;
    }
    gid -= 9216;
    if (gid < 131072) {
        int idx = gid;
        int e = idx & 7;
        int lane = (idx >> 3) & 63;
        int seg8 = (idx >> 9) & 7;
        int u = idx >> 12;
        int cb = u % 2, tap = u / 2;
        int lr = lane & 15, lc = lane >> 4;
        int kc = seg8 >> 2, sg = seg8 & 3;
        int co = cb * 64 + sg * 16 + lr;
        int ci = kc * 32 + lc * 8 + e;
        we2[idx] = f2us(e_w2[((size_t)co * 64 + ci) * 16 + tap]);
        return;
    }
    gid -= 131072;
    if (gid < 393216) {
        int idx = gid;
        int ci = idx % 128;
        int co = (idx / 128) % 192;
        int kk = idx / (128 * 192);
        we3[idx] = f2us(e_w3[((size_t)co * 128 + ci) * 16 + kk]);
        return;
    }
    gid -= 393216;
    if (gid < 49152) {
        int idx = gid;
        int ci = idx % 192;
        int co = (idx / 192) % 256;
        we4[idx] = f2us(e_w4[(size_t)co * 192 + ci]);
        return;
    }
    gid -= 49152;
    if (gid < 49152) {
        int idx = gid;
        int ci = idx % 256;
        int co = idx / 256;
        wd1[idx] = f2us(d_w1[(size_t)ci * 192 + co]);
        return;
    }
    gid -= 49152;
    if (gid < 393216) {
        int idx = gid;
        int e = idx & 7;
        int lane = (idx >> 3) & 63;
        int seg8 = (idx >> 9) & 7;
        int u = idx >> 12;
        int cb = u % 2;
        int u2 = u / 2;
        int cc = u2 % 3;
        int tk = u2 / 3;
        int kidx = tk & 3, cls = tk >> 2;
        int lr = lane & 15, lc = lane >> 4;
        int kc = seg8 >> 2, sg = seg8 & 3;
        int co = cb * 64 + sg * 16 + lr;
        int ci = cc * 64 + kc * 32 + lc * 8 + e;
        int ohp = cls >> 1, owp = cls & 1;
        int kh = ((ohp + 1) & 1) + 2 * (kidx >> 1);
        int kw = ((owp + 1) & 1) + 2 * (kidx & 1);
        wd2[idx] = f2us(d_w2[((size_t)ci * 128 + co) * 16 + kh * 4 + kw]);
        return;
    }
    gid -= 393216;
    if (gid < 131072) {
        int idx = gid;
        int e = idx & 7;
        int lane = (idx >> 3) & 63;
        int seg8 = (idx >> 9) & 7;
        int u2 = idx >> 12;
        int cc = u2 % 2;
        int tk = u2 / 2;
        int kidx = tk & 3, cls = tk >> 2;
        int lr = lane & 15, lc = lane >> 4;
        int kc = seg8 >> 2, sg = seg8 & 3;
        int co = sg * 16 + lr;
        int ci = cc * 64 + kc * 32 + lc * 8 + e;
        int ohp = cls >> 1, owp = cls & 1;
        int kh = ((ohp + 1) & 1) + 2 * (kidx >> 1);
        int kw = ((owp + 1) & 1) + 2 * (kidx & 1);
        wd3[idx] = f2us(d_w3[((size_t)ci * 64 + co) * 16 + kh * 4 + kw]);
        return;
    }
    gid -= 131072;
    if (gid < 128) zpage[gid] = 0;
}

// ---------------------------------------------------------------------------
// E1: FUSED im2col + MFMA GEMM. Output CLASS-MAJOR; fused BN partials.
// ---------------------------------------------------------------------------
__global__ __launch_bounds__(TPB) void e1_gemm(
    const float* __restrict__ x, const unsigned short* __restrict__ wrep,
    const float* __restrict__ bias, unsigned short* __restrict__ yout,
    float* __restrict__ part, int N)
{
    __shared__ __align__(16) unsigned short Ab[8 * 512];   // 8 KB
    __shared__ __align__(16) unsigned short Bb[4 * 512];   // 4 KB

    const int t = threadIdx.x, lane = t & 63, wave = t >> 6;
    const int wm = wave >> 1, wn = wave & 1;
    const int m0 = (int)blockIdx.x * 128;
    const int lr = lane & 15, lc = lane >> 4;

    gl_lds16(wrep + (size_t)(wave * 16 + lr) * 32 + lc * 8, &Bb[wave * 512]);

    {
        int r = m0 + (t >> 1);
        int h = t & 1;
        int n = r >> 12, oh = (r >> 6) & 63, ow = r & 63;
        unsigned short rowv[16];
#pragma unroll
        for (int kk = 0; kk < 16; kk++) {
            int k = h * 16 + kk;
            float v = 0.f;
            if (k < 27) {
                int ci = k / 9, tap = k % 9, kh = tap / 3, kw = tap % 3;
                int ih = oh - 1 + kh, iw = ow - 1 + kw;
                if ((unsigned)ih < 64u && (unsigned)iw < 64u)
                    v = x[(((size_t)n * 3 + ci) * 64 + ih) * 64 + iw];
            }
            rowv[kk] = f2us(v);
        }
        int rl = (t >> 1) & 15;
        int s = (t >> 1) >> 4;
        int base = s * 512 + (h * 32 + rl) * 8;   // shorts
        *(int4*)&Ab[base] = *(const int4*)&rowv[0];
        *(int4*)&Ab[base + 128] = *(const int4*)&rowv[8];
    }
    __syncthreads();

    v4f acc[4][2];
#pragma unroll
    for (int i = 0; i < 4; i++)
#pragma unroll
        for (int j = 0; j < 2; j++)
#pragma unroll
            for (int r = 0; r < 4; r++) acc[i][j][r] = 0.f;

    v8s a[4], b[2];
#pragma unroll
    for (int i = 0; i < 4; i++)
        a[i] = *(const v8s*)&Ab[(wm * 4 + i) * 512 + lane * 8];
#pragma unroll
    for (int j = 0; j < 2; j++)
        b[j] = *(const v8s*)&Bb[(wn * 2 + j) * 512 + lane * 8];
#pragma unroll
    for (int i = 0; i < 4; i++)
#pragma unroll
        for (int j = 0; j < 2; j++)
            acc[i][j] = __builtin_amdgcn_mfma_f32_16x16x32_bf16(a[i], b[j], acc[i][j], 0, 0, 0);

    float sloc[2], qloc[2];
#pragma unroll
    for (int j = 0; j < 2; j++) { sloc[j] = 0.f; qloc[j] = 0.f; }

#pragma unroll
    for (int i = 0; i < 4; i++) {
        int mr = wm * 64 + i * 16 + (lane >> 4) * 4;
#pragma unroll
        for (int j = 0; j < 2; j++) {
            int col = wn * 32 + j * 16 + (lane & 15);
            float bs = bias[col];
#pragma unroll
            for (int r = 0; r < 4; r++) {
                int row = m0 + mr + r;
                int n = row >> 12, oh = (row >> 6) & 63, ow = row & 63;
                int cls = ((oh & 1) << 1) | (ow & 1);
                size_t crow = ((((size_t)cls * N + n) * 32 + (oh >> 1)) * 32 + (ow >> 1));
                float v = acc[i][j][r] + bs;
                yout[crow * 64 + col] = f2us(v);
                sloc[j] += v;
                qloc[j] += v * v;
            }
        }
    }

    __syncthreads();
    float* red = (float*)Ab;
    for (int i = t; i < 128; i += TPB) red[i] = 0.f;
    __syncthreads();
#pragma unroll
    for (int j = 0; j < 2; j++) {
        float s = sloc[j], qv = qloc[j];
        s += __shfl_xor(s, 16); s += __shfl_xor(s, 32);
        qv += __shfl_xor(qv, 16); qv += __shfl_xor(qv, 32);
        if ((lane >> 4) == 0) {
            int cl = wn * 32 + j * 16 + (lane & 15);
            atomicAdd(&red[cl], s);
            atomicAdd(&red[64 + cl], qv);
        }
    }
    __syncthreads();
    int PB = (int)gridDim.x, pb = (int)blockIdx.x;
    for (int i = t; i < 64; i += TPB) {
        part[(size_t)i * PB + pb] = red[i];
        part[(size_t)(64 + i) * PB + pb] = red[64 + i];
    }
}

// ---------------------------------------------------------------------------
// Forward conv k4 s2 p1 with CLASS-MAJOR input, contiguous-DMA staging.
// ---------------------------------------------------------------------------
template<int CIN, int COUT, int HO, int WO, int NCB>
__global__ __launch_bounds__(TPB) void conv_c(
    const unsigned short* __restrict__ xin, const unsigned short* __restrict__ wrep,
    const float* __restrict__ bias, unsigned short* __restrict__ yout,
    float* __restrict__ part, const unsigned short* __restrict__ zpage, int N)
{
    constexpr int NCI = CIN / 64;
    constexpr int NIT = 16 * NCI;
    __shared__ __align__(16) unsigned short Ab[2][16 * 1024];  // 64 KB
    __shared__ __align__(16) unsigned short Bb[2][8 * 512];    // 16 KB

    const int t = threadIdx.x, lane = t & 63, wave = t >> 6;
    int gdec = (int)blockIdx.x >> 3, xs = (int)blockIdx.x & 7;
    int cb = 0;
    if (NCB >= 2) { cb = gdec % NCB; gdec /= NCB; }
    const int tile = (gdec << 3) + xs;
    const int m0 = tile * 256;
    const int co0 = cb * 64;
    const int lr = lane & 15, lc = lane >> 4;

    const int jr7 = lane >> 3;
    const int sw = ((lane & 7) ^ jr7) * 8;   // shorts

    int n_[4], oh_[4], ow0_[4];
#pragma unroll
    for (int q = 0; q < 4; q++) {
        int r0 = m0 + (wave * 4 + q) * 16;
        n_[q] = r0 / (HO * WO);
        int rem = r0 % (HO * WO);
        oh_[q] = rem / WO;
        ow0_[q] = rem % WO;
    }

    v4f acc[4][4];
#pragma unroll
    for (int i = 0; i < 4; i++)
#pragma unroll
        for (int j = 0; j < 4; j++)
#pragma unroll
            for (int r = 0; r < 4; r++) acc[i][j][r] = 0.f;

    auto stage = [&](int it, int buf) {
        const int tap = it / NCI, cc = it % NCI;
        const int kh = tap >> 2, kw = tap & 3;
        const int dcls = (((kh + 1) & 1) << 1) | ((kw + 1) & 1);
        const int dh2 = (kh - 1) >> 1;
        const int dw2 = (kw - 1) >> 1;
#pragma unroll
        for (int q = 0; q < 4; q++) {
            const int ih2 = oh_[q] + dh2;
            const bool ihv = (unsigned)ih2 < (unsigned)HO;
#pragma unroll
            for (int h = 0; h < 2; h++) {
                int iw2 = ow0_[q] + h * 8 + jr7 + dw2;
                bool av = ihv && (unsigned)iw2 < (unsigned)WO;
                size_t ab = ((((size_t)dcls * N + n_[q]) * HO + ih2) * WO + iw2) * CIN;
                const unsigned short* src = av ? xin + ab + cc * 64 + sw : zpage;
                gl_lds16(src, &Ab[buf][(wave * 4 + q) * 1024 + h * 512]);
            }
        }
        const unsigned short* wb = wrep
            + ((size_t)(tap * NCI + cc) * NCB + cb) * 4096;
        gl_lds16(wb + wave * 512 + lane * 8, &Bb[buf][wave * 512]);
        gl_lds16(wb + (4 + wave) * 512 + lane * 8, &Bb[buf][(4 + wave) * 512]);
    };

    auto compute = [&](int it, int buf) {
#pragma unroll
        for (int kc = 0; kc < 2; kc++) {
            v8s a[4], b[4];
#pragma unroll
            for (int i = 0; i < 4; i++)
                a[i] = *(const v8s*)&Ab[buf][(wave * 4 + i) * 1024 + lr * 64
                        + ((kc * 32 + lc * 8) ^ ((lr & 7) << 3))];
#pragma unroll
            for (int j = 0; j < 4; j++)
                b[j] = *(const v8s*)&Bb[buf][(kc * 4 + j) * 512 + lane * 8];
#pragma unroll
            for (int i = 0; i < 4; i++)
#pragma unroll
                for (int j = 0; j < 4; j++)
                    acc[i][j] = __builtin_amdgcn_mfma_f32_16x16x32_bf16(a[i], b[j], acc[i][j], 0, 0, 0);
        }
    };

    stage(0, 0);
    __syncthreads();

#pragma unroll
    for (int it = 0; it < NIT; ++it) {
        const int buf = it & 1;
        if (it + 1 < NIT) stage(it + 1, buf ^ 1);
        compute(it, buf);
        __syncthreads();
    }

    float sloc[4], qloc[4];
#pragma unroll
    for (int j = 0; j < 4; j++) { sloc[j] = 0.f; qloc[j] = 0.f; }

#pragma unroll
    for (int i = 0; i < 4; i++) {
        int mr = wave * 64 + i * 16 + (lane >> 4) * 4;
#pragma unroll
        for (int j = 0; j < 4; j++) {
            int col = co0 + j * 16 + (lane & 15);
            float bs = bias[col];
#pragma unroll
            for (int r = 0; r < 4; r++) {
                size_t gi = (size_t)(m0 + mr + r) * COUT + col;
                float v = acc[i][j][r] + bs;
                yout[gi] = f2us(v);
                sloc[j] += v;
                qloc[j] += v * v;
            }
        }
    }

    float* red = (float*)Ab;
    for (int i = t; i < 128; i += TPB) red[i] = 0.f;
    __syncthreads();
#pragma unroll
    for (int j = 0; j < 4; j++) {
        float s = sloc[j], qv = qloc[j];
        s += __shfl_xor(s, 16); s += __shfl_xor(s, 32);
        qv += __shfl_xor(qv, 16); qv += __shfl_xor(qv, 32);
        if ((lane >> 4) == 0) {
            int cl = j * 16 + (lane & 15);
            atomicAdd(&red[cl], s);
            atomicAdd(&red[64 + cl], qv);
        }
    }
    __syncthreads();
    const int TILES = (N * HO * WO) >> 8;
    const int pb = tile;
    for (int i = t; i < 64; i += TPB) {
        part[(size_t)(co0 + i) * TILES + pb] = red[i];
        part[(size_t)(COUT + co0 + i) * TILES + pb] = red[64 + i];
    }
}

// ---------------------------------------------------------------------------
// MFMA implicit-GEMM conv, DMA-staged (scattered), BK=64 — E3 / E4 / D1.
// ---------------------------------------------------------------------------
template<int CIN, int COUT, int HIN, int WIN, int K, int S, int P, int BN,
         int OUTM, int NYB>
__global__ __launch_bounds__(TPB) void conv_mfma(
    const unsigned short* __restrict__ xin, const unsigned short* __restrict__ wrep,
    const float* __restrict__ bias, void* __restrict__ yout, void* __restrict__ yout2,
    float* __restrict__ part, const unsigned short* __restrict__ zpage, int N)
{
    constexpr int HOUT = (HIN + 2 * P - K) / S + 1;
    constexpr int WOUT = (WIN + 2 * P - K) / S + 1;
    constexpr int RN = BN / 32;
    constexpr int BSEG = BN / 16;
    constexpr int NCI = CIN / 64;
    constexpr int NIT = K * K * NCI;
    __shared__ __align__(16) unsigned short Ab[2][16 * 512];
    __shared__ __align__(16) unsigned short Bb[2][2 * BSEG * 512];

    const int t = threadIdx.x, lane = t & 63, wave = t >> 6;
    const int wm = wave >> 1, wn = wave & 1;
    int m0, co0;
    if (NYB == 2) {
        int g = (int)blockIdx.x >> 3, xs = (int)blockIdx.x & 7;
        co0 = (g & 1) * BN;
        m0 = (((g >> 1) << 3) + xs) * 128;
    } else {
        m0 = (int)blockIdx.x * 128;
        co0 = 0;
    }
    const int lr = lane & 15, lc = lane >> 4;

    int n_[2], oh_[2], ow_[2];
#pragma unroll
    for (int i = 0; i < 2; i++) {
        int r = m0 + (wave + 4 * i) * 16 + lr;
        n_[i] = r / (HOUT * WOUT);
        int rem = r % (HOUT * WOUT);
        oh_[i] = rem / WOUT;
        ow_[i] = rem % WOUT;
    }

    v4f acc[4][RN];
#pragma unroll
    for (int i = 0; i < 4; i++)
#pragma unroll
        for (int j = 0; j < RN; j++)
#pragma unroll
            for (int r = 0; r < 4; r++) acc[i][j][r] = 0.f;

    auto do_stage = [&](int it, int pb) {
        const int kk = it / NCI;
        const int ci0 = (it % NCI) * 64;
        const int kh = kk / K, kw = kk % K;
#pragma unroll
        for (int i = 0; i < 2; i++) {
            int ih = oh_[i] * S - P + kh;
            int iw = ow_[i] * S - P + kw;
            bool av = (unsigned)ih < (unsigned)HIN && (unsigned)iw < (unsigned)WIN;
            const unsigned short* b0 = av
                ? xin + (((size_t)n_[i] * HIN + ih) * WIN + iw) * CIN + lc * 8 + ci0
                : zpage;
            gl_lds16(b0, &Ab[pb][(wave + 4 * i) * 512]);
            gl_lds16(av ? b0 + 32 : zpage, &Ab[pb][(8 + wave + 4 * i) * 512]);
        }
        const unsigned short* wt = wrep + (size_t)kk * COUT * CIN;
#pragma unroll
        for (int i = 0; i < 2; i++) {
            int sgb = wave + 4 * i;
            if (sgb < BSEG) {
                const unsigned short* wb =
                    wt + (size_t)(co0 + sgb * 16 + lr) * CIN + ci0 + lc * 8;
                gl_lds16(wb, &Bb[pb][sgb * 512]);
                gl_lds16(wb + 32, &Bb[pb][(BSEG + sgb) * 512]);
            }
        }
    };

    do_stage(0, 0);
    __syncthreads();

    for (int it = 0; it < NIT; ++it) {
        const int pb = it & 1;
        if (it + 1 < NIT) do_stage(it + 1, pb ^ 1);

#pragma unroll
        for (int kc = 0; kc < 2; kc++) {
            v8s a[4], b[RN];
#pragma unroll
            for (int i = 0; i < 4; i++)
                a[i] = *(const v8s*)&Ab[pb][(kc * 8 + wm * 4 + i) * 512 + lane * 8];
#pragma unroll
            for (int j = 0; j < RN; j++)
                b[j] = *(const v8s*)&Bb[pb][(kc * BSEG + wn * RN + j) * 512 + lane * 8];
#pragma unroll
            for (int i = 0; i < 4; i++)
#pragma unroll
                for (int j = 0; j < RN; j++)
                    acc[i][j] = __builtin_amdgcn_mfma_f32_16x16x32_bf16(a[i], b[j], acc[i][j], 0, 0, 0);
        }
        __syncthreads();
    }

    float sloc[RN], qloc[RN];
#pragma unroll
    for (int j = 0; j < RN; j++) { sloc[j] = 0.f; qloc[j] = 0.f; }

#pragma unroll
    for (int i = 0; i < 4; i++) {
        int mr = wm * 64 + i * 16 + (lane >> 4) * 4;
#pragma unroll
        for (int j = 0; j < RN; j++) {
            int col = co0 + wn * (BN / 2) + j * 16 + (lane & 15);
            float bs = bias[col];
#pragma unroll
            for (int r = 0; r < 4; r++) {
                size_t g = (size_t)(m0 + mr + r) * COUT + col;
                float v = acc[i][j][r] + bs;
                if (OUTM == 2) {
                    unsigned short h = f2us(v);
                    ((unsigned short*)yout)[g] = h;
                    ((unsigned short*)yout2)[g] = f2us(v - us2f(h));
                } else {
                    ((unsigned short*)yout)[g] = f2us(v);
                    sloc[j] += v;
                    qloc[j] += v * v;
                }
            }
        }
    }

    if (OUTM == 0) {
        __syncthreads();
        float* red = (float*)Ab;
        for (int i = t; i < 2 * BN; i += TPB) red[i] = 0.f;
        __syncthreads();
#pragma unroll
        for (int j = 0; j < RN; j++) {
            float s = sloc[j], qv = qloc[j];
            s += __shfl_xor(s, 16); s += __shfl_xor(s, 32);
            qv += __shfl_xor(qv, 16); qv += __shfl_xor(qv, 32);
            if ((lane >> 4) == 0) {
                int cl = wn * (BN / 2) + j * 16 + (lane & 15);
                atomicAdd(&red[cl], s);
                atomicAdd(&red[BN + cl], qv);
            }
        }
        __syncthreads();
        int pb = (NYB == 2) ? (m0 >> 7) : (int)blockIdx.x;
        int PB = (NYB == 2) ? ((int)gridDim.x >> 1) : (int)gridDim.x;
        for (int i = t; i < BN; i += TPB) {
            int col = co0 + i;
            part[(size_t)col * PB + pb] = red[i];
            part[(size_t)(COUT + col) * PB + pb] = red[BN + i];
        }
    }
}

// ---------------------------------------------------------------------------
// Transposed conv k4 s2 p1, CONTIGUOUS-DMA (barriered) — used by D2 (NCB=2).
// ---------------------------------------------------------------------------
template<int CIN, int COUT, int HIN, int WIN, int NCB, int IN_CLS>
__global__ __launch_bounds__(TPB) void convt_c(
    const unsigned short* __restrict__ xin, const unsigned short* __restrict__ wrep,
    const float* __restrict__ bias, unsigned short* __restrict__ yout,
    float* __restrict__ part, const unsigned short* __restrict__ zpage, int N)
{
    constexpr int NCI = CIN / 64;
    constexpr int NIT = 4 * NCI;
    __shared__ __align__(16) unsigned short Ab[2][16 * 1024];  // 64 KB
    __shared__ __align__(16) unsigned short Bb[2][8 * 512];    // 16 KB

    const int t = threadIdx.x, lane = t & 63, wave = t >> 6;
    int gdec = (int)blockIdx.x >> 3, xs = (int)blockIdx.x & 7;
    int cb = 0;
    if (NCB == 2) { cb = gdec & 1; gdec >>= 1; }
    const int cls = gdec & 3;
    const int tile = ((gdec >> 2) << 3) + xs;
    const int m0 = tile * 256;
    const int co0 = cb * 64;
    const int ohp = cls >> 1, owp = cls & 1;
    const int khb = (ohp + 1) & 1, kwb = (owp + 1) & 1;
    const int dh0 = (ohp + 1 - khb) >> 1, dw0 = (owp + 1 - kwb) >> 1;
    const int lr = lane & 15, lc = lane >> 4;

    const int jr7 = lane >> 3;
    const int sw = ((lane & 7) ^ jr7) * 8;   // shorts

    int n_[4], i_[4], j0_[4];
#pragma unroll
    for (int q = 0; q < 4; q++) {
        int r0 = m0 + (wave * 4 + q) * 16;
        n_[q] = r0 / (HIN * WIN);
        int rem = r0 % (HIN * WIN);
        i_[q] = rem / WIN;
        j0_[q] = rem % WIN;
    }

    v4f acc[4][4];
#pragma unroll
    for (int i = 0; i < 4; i++)
#pragma unroll
        for (int j = 0; j < 4; j++)
#pragma unroll
            for (int r = 0; r < 4; r++) acc[i][j][r] = 0.f;

    auto stage = [&](int it, int buf) {
        const int tap = it / NCI, cc = it % NCI;
        const int dh = dh0 - (tap >> 1);
        const int dw = dw0 - (tap & 1);
#pragma unroll
        for (int q = 0; q < 4; q++) {
            const int ih = i_[q] + dh;
            const bool ihv = (unsigned)ih < (unsigned)HIN;
#pragma unroll
            for (int h = 0; h < 2; h++) {
                int iw = j0_[q] + h * 8 + jr7 + dw;
                bool av = ihv && (unsigned)iw < (unsigned)WIN;
                size_t ab;
                if (IN_CLS) {
                    int clsi = ((ih & 1) << 1) | (iw & 1);
                    ab = ((((size_t)clsi * N + n_[q]) * (HIN / 2) + (ih >> 1)) * (WIN / 2)
                         + (iw >> 1)) * CIN;
                } else {
                    ab = (((size_t)n_[q] * HIN + ih) * WIN + iw) * CIN;
                }
                const unsigned short* src = av ? xin + ab + cc * 64 + sw : zpage;
                gl_lds16(src, &Ab[buf][(wave * 4 + q) * 1024 + h * 512]);
            }
        }
        const unsigned short* wb = wrep
            + ((size_t)((cls * 4 + tap) * NCI + cc) * NCB + cb) * 4096;
        gl_lds16(wb + wave * 512 + lane * 8, &Bb[buf][wave * 512]);
        gl_lds16(wb + (4 + wave) * 512 + lane * 8, &Bb[buf][(4 + wave) * 512]);
    };

    auto compute = [&](int it, int buf) {
#pragma unroll
        for (int kc = 0; kc < 2; kc++) {
            v8s a[4], b[4];
#pragma unroll
            for (int i = 0; i < 4; i++)
                a[i] = *(const v8s*)&Ab[buf][(wave * 4 + i) * 1024 + lr * 64
                        + ((kc * 32 + lc * 8) ^ ((lr & 7) << 3))];
#pragma unroll
            for (int j = 0; j < 4; j++)
                b[j] = *(const v8s*)&Bb[buf][(kc * 4 + j) * 512 + lane * 8];
#pragma unroll
            for (int i = 0; i < 4; i++)
#pragma unroll
                for (int j = 0; j < 4; j++)
                    acc[i][j] = __builtin_amdgcn_mfma_f32_16x16x32_bf16(a[i], b[j], acc[i][j], 0, 0, 0);
        }
    };

    stage(0, 0);
    __syncthreads();

#pragma unroll
    for (int it = 0; it < NIT; ++it) {
        const int buf = it & 1;
        if (it + 1 < NIT) stage(it + 1, buf ^ 1);
        compute(it, buf);
        __syncthreads();
    }

    float sloc[4], qloc[4];
#pragma unroll
    for (int j = 0; j < 4; j++) { sloc[j] = 0.f; qloc[j] = 0.f; }

    const size_t clsbase = (size_t)cls * N * HIN * WIN;
#pragma unroll
    for (int i = 0; i < 4; i++) {
        int mr = wave * 64 + i * 16 + (lane >> 4) * 4;
#pragma unroll
        for (int j = 0; j < 4; j++) {
            int col = co0 + j * 16 + (lane & 15);
            float bs = bias[col];
#pragma unroll
            for (int r = 0; r < 4; r++) {
                size_t gi = (clsbase + m0 + mr + r) * COUT + col;
                float v = acc[i][j][r] + bs;
                yout[gi] = f2us(v);
                sloc[j] += v;
                qloc[j] += v * v;
            }
        }
    }

    float* red = (float*)Ab;
    for (int i = t; i < 128; i += TPB) red[i] = 0.f;
    __syncthreads();
#pragma unroll
    for (int j = 0; j < 4; j++) {
        float s = sloc[j], qv = qloc[j];
        s += __shfl_xor(s, 16); s += __shfl_xor(s, 32);
        qv += __shfl_xor(qv, 16); qv += __shfl_xor(qv, 32);
        if ((lane >> 4) == 0) {
            int cl = j * 16 + (lane & 15);
            atomicAdd(&red[cl], s);
            atomicAdd(&red[64 + cl], qv);
        }
    }
    __syncthreads();
    const int TILES = (N * HIN * WIN) >> 8;   // m-tiles per class
    const int PB = 4 * TILES;
    const int pb = cls * TILES + tile;
    for (int i = t; i < 64; i += TPB) {
        part[(size_t)(co0 + i) * PB + pb] = red[i];
        part[(size_t)(COUT + co0 + i) * PB + pb] = red[64 + i];
    }
}

// ---------------------------------------------------------------------------
// Transposed conv, BARRIER-FREE single-buffer + PRE-COMPUTED ADDRESSES (D3
// pilot v3). All 32 (q,tap,h) per-lane source offsets are loop-invariant ->
// hoisted to the prologue as int32 byte-offsets from xin (OOB lanes store
// zpage-xin; +cc*128B stays inside the 256-B zero page). Per-iteration
// staging is now just base+offset adds, removing ~240 cycles of serial
// address math from inside the vmcnt/lgkmcnt-guarded loop region.
// Same addresses/DMA order => bitwise-identical accumulation.
// ---------------------------------------------------------------------------
template<int CIN, int COUT, int HIN, int WIN, int IN_CLS>
__global__ __launch_bounds__(TPB) void convt_nb(
    const unsigned short* __restrict__ xin, const unsigned short* __restrict__ wrep,
    const float* __restrict__ bias, unsigned short* __restrict__ yout,
    float* __restrict__ part, const unsigned short* __restrict__ zpage, int N)
{
    constexpr int NCI = CIN / 64;
    constexpr int NIT = 4 * NCI;
    __shared__ __align__(16) unsigned short Ab[16 * 1024];   // 32 KB (single)
    __shared__ float red[128];

    const int t = threadIdx.x, lane = t & 63, wave = t >> 6;
    int gdec = (int)blockIdx.x >> 3, xs = (int)blockIdx.x & 7;
    const int cls = gdec & 3;
    const int tile = ((gdec >> 2) << 3) + xs;
    const int m0 = tile * 256;
    const int ohp = cls >> 1, owp = cls & 1;
    const int khb = (ohp + 1) & 1, kwb = (owp + 1) & 1;
    const int dh0 = (ohp + 1 - khb) >> 1, dw0 = (owp + 1 - kwb) >> 1;
    const int lr = lane & 15, lc = lane >> 4;

    const int jr7 = lane >> 3;
    const int sw = ((lane & 7) ^ jr7) * 8;   // shorts

    int n_[4], i_[4], j0_[4];
#pragma unroll
    for (int q = 0; q < 4; q++) {
        int r0 = m0 + (wave * 4 + q) * 16;
        n_[q] = r0 / (HIN * WIN);
        int rem = r0 % (HIN * WIN);
        i_[q] = rem / WIN;
        j0_[q] = rem % WIN;
    }

    // hoisted per-lane byte offsets [q][tap][h] (int32; OOB -> zpage)
    int aoffb[4][4][2];
    {
        const int zdb = (int)((const char*)zpage - (const char*)xin);
#pragma unroll
        for (int q = 0; q < 4; q++) {
#pragma unroll
            for (int tap = 0; tap < 4; tap++) {
                const int dh = dh0 - (tap >> 1);
                const int dw = dw0 - (tap & 1);
                const int ih = i_[q] + dh;
                const bool ihv = (unsigned)ih < (unsigned)HIN;
#pragma unroll
                for (int h = 0; h < 2; h++) {
                    int iw = j0_[q] + h * 8 + jr7 + dw;
                    bool av = ihv && (unsigned)iw < (unsigned)WIN;
                    size_t ab;
                    if (IN_CLS) {
                        int clsi = ((ih & 1) << 1) | (iw & 1);
                        ab = ((((size_t)clsi * N + n_[q]) * (HIN / 2) + (ih >> 1)) * (WIN / 2)
                             + (iw >> 1)) * CIN;
                    } else {
                        ab = (((size_t)n_[q] * HIN + ih) * WIN + iw) * CIN;
                    }
                    aoffb[q][tap][h] = av ? (int)((ab + sw) * 2) : zdb;
                }
            }
        }
    }

    v4f acc[4][4];
#pragma unroll
    for (int i = 0; i < 4; i++)
#pragma unroll
        for (int j = 0; j < 4; j++)
#pragma unroll
            for (int r = 0; r < 4; r++) acc[i][j][r] = 0.f;

    // A staging: 8 DMAs from precomputed offsets (cc*128 B stays inside the
    // zero page on OOB lanes, so the add is unconditional)
    auto stageA = [&](int it) {
        const int tap = it / NCI, cc = it % NCI;
#pragma unroll
        for (int q = 0; q < 4; q++) {
#pragma unroll
            for (int h = 0; h < 2; h++) {
                const unsigned short* src = (const unsigned short*)
                    ((const char*)xin + aoffb[q][tap][h] + cc * 128);
                gl_lds16(src, &Ab[(wave * 4 + q) * 1024 + h * 512]);
            }
        }
    };
    auto loadB = [&](int it, v8s (&breg)[8]) {
        const int tap = it / NCI, cc = it % NCI;
        const unsigned short* wb = wrep + (size_t)((cls * 4 + tap) * NCI + cc) * 4096;
#pragma unroll
        for (int s = 0; s < 8; s++)
            breg[s] = *(const v8s*)(wb + s * 512 + lane * 8);
    };
    auto computeIt = [&](const v8s (&breg)[8]) {
#pragma unroll
        for (int kc = 0; kc < 2; kc++) {
            v8s a[4];
#pragma unroll
            for (int i = 0; i < 4; i++)
                a[i] = *(const v8s*)&Ab[(wave * 4 + i) * 1024 + lr * 64
                        + ((kc * 32 + lc * 8) ^ ((lr & 7) << 3))];
#pragma unroll
            for (int i = 0; i < 4; i++)
#pragma unroll
                for (int j = 0; j < 4; j++)
                    acc[i][j] = __builtin_amdgcn_mfma_f32_16x16x32_bf16(a[i], breg[kc * 4 + j], acc[i][j], 0, 0, 0);
        }
    };

    v8s bA[8], bB[8];
    stageA(0); loadB(0, bA); loadB(1, bB);

#pragma unroll
    for (int it = 0; it < NIT; ++it) {
        // retire stageA(it)+loadB(it); leave loadB(it+1) in flight
        if (it + 1 < NIT) { asm volatile("s_waitcnt vmcnt(8)" ::: "memory"); }
        else              { asm volatile("s_waitcnt vmcnt(0)" ::: "memory"); }
        __builtin_amdgcn_sched_barrier(0);
        if ((it & 1) == 0) computeIt(bA); else computeIt(bB);
        if (it + 1 < NIT) {
            // same-wave LDS WAR: all ds_reads of compute(it) retired first
            asm volatile("s_waitcnt lgkmcnt(0)" ::: "memory");
            __builtin_amdgcn_sched_barrier(0);
            stageA(it + 1);
            if (it + 2 < NIT) {
                if ((it & 1) == 0) loadB(it + 2, bA); else loadB(it + 2, bB);
            }
        }
    }

    float sloc[4], qloc[4];
#pragma unroll
    for (int j = 0; j < 4; j++) { sloc[j] = 0.f; qloc[j] = 0.f; }

    const size_t clsbase = (size_t)cls * N * HIN * WIN;
#pragma unroll
    for (int i = 0; i < 4; i++) {
        int mr = wave * 64 + i * 16 + (lane >> 4) * 4;
#pragma unroll
        for (int j = 0; j < 4; j++) {
            int col = j * 16 + (lane & 15);
            float bs = bias[col];
#pragma unroll
            for (int r = 0; r < 4; r++) {
                size_t gi = (clsbase + m0 + mr + r) * COUT + col;
                float v = acc[i][j][r] + bs;
                yout[gi] = f2us(v);
                sloc[j] += v;
                qloc[j] += v * v;
            }
        }
    }

    for (int i = t; i < 128; i += TPB) red[i] = 0.f;
    __syncthreads();
#pragma unroll
    for (int j = 0; j < 4; j++) {
        float s = sloc[j], qv = qloc[j];
        s += __shfl_xor(s, 16); s += __shfl_xor(s, 32);
        qv += __shfl_xor(qv, 16); qv += __shfl_xor(qv, 32);
        if ((lane >> 4) == 0) {
            int cl = j * 16 + (lane & 15);
            atomicAdd(&red[cl], s);
            atomicAdd(&red[64 + cl], qv);
        }
    }
    __syncthreads();
    const int TILES = (N * HIN * WIN) >> 8;   // m-tiles per class
    const int PB = 4 * TILES;
    const int pb = cls * TILES + tile;
    for (int i = t; i < 64; i += TPB) {
        part[(size_t)i * PB + pb] = red[i];
        part[(size_t)(COUT + i) * PB + pb] = red[64 + i];
    }
}

// ---------------------------------------------------------------------------
// BN reduce / apply.
// ---------------------------------------------------------------------------
template<int C>
__global__ __launch_bounds__(64) void bn_reduce2(
    const float* __restrict__ part, float* __restrict__ st, int B)
{
    int i = blockIdx.x;
    int lane = threadIdx.x;
    float s = 0.f;
    for (int b = lane; b < B; b += 64) s += part[(size_t)i * B + b];
#pragma unroll
    for (int off = 1; off < 64; off <<= 1) s += __shfl_xor(s, off);
    if (lane == 0) st[i] = s;
}

template<int C>
__global__ __launch_bounds__(TPB) void bn_apply_v(
    unsigned short* __restrict__ x, const float* __restrict__ st,
    const float* __restrict__ g, const float* __restrict__ be, int M)
{
    __shared__ float sc[C], sh[C];
    int t = threadIdx.x;
    float cnt = (float)M;
    for (int c = t; c < C; c += TPB) {
        float m = st[c] / cnt;
        float v = st[C + c] / cnt - m * m;
        float s = g[c] * rsqrtf(v + 1e-5f);
        sc[c] = s;
        sh[c] = be[c] - m * s;
    }
    __syncthreads();
    constexpr int GPT = C / 8;
    size_t tot = (size_t)M * GPT;
    for (size_t slot = (size_t)blockIdx.x * TPB + t; slot < tot;
         slot += (size_t)gridDim.x * TPB) {
        int c0 = (int)(slot % GPT) * 8;
        int4 v = *(int4*)(x + slot * 8);
        unsigned int* vu = (unsigned int*)&v;
#pragma unroll
        for (int k = 0; k < 4; k++) {
            float f0 = fmaxf(us2f(vu[k] & 0xffffu) * sc[c0 + 2 * k] + sh[c0 + 2 * k], 0.f);
            float f1 = fmaxf(us2f(vu[k] >> 16) * sc[c0 + 2 * k + 1] + sh[c0 + 2 * k + 1], 0.f);
            vu[k] = (unsigned int)f2us(f0) | ((unsigned int)f2us(f1) << 16);
        }
        *(int4*)(x + slot * 8) = v;
    }
}

// ---------------------------------------------------------------------------
// VQ stage 1: codebook split hi/lo bf16 + cn2.
// ---------------------------------------------------------------------------
__global__ __launch_bounds__(TPB) void cb_prep(
    const float* __restrict__ cb, unsigned short* __restrict__ chb,
    unsigned short* __restrict__ clb, float* __restrict__ cn2)
{
    int j = blockIdx.x, d = threadIdx.x;
    float v = cb[j * 256 + d];
    unsigned short h = f2us(v);
    chb[j * 256 + d] = h;
    clb[j * 256 + d] = f2us(v - us2f(h));
    float s = v * v;
#pragma unroll
    for (int off = 1; off < 64; off <<= 1) s += __shfl_xor(s, off);
    __shared__ float p[4];
    if ((d & 63) == 0) p[d >> 6] = s;
    __syncthreads();
    if (d == 0) cn2[j] = p[0] + p[1] + p[2] + p[3];
}

// ---------------------------------------------------------------------------
// VQ stage 2: split-bf16 MFMA distance GEMM with fused per-wave argmin.
// ---------------------------------------------------------------------------
__global__ __launch_bounds__(TPB) void vq_gemm(
    const unsigned short* __restrict__ zh, const unsigned short* __restrict__ zl,
    const unsigned short* __restrict__ chb, const unsigned short* __restrict__ clb,
    const float* __restrict__ cn2, float* __restrict__ valp, int* __restrict__ idxp)
{
    __shared__ __align__(16) unsigned short Ah[2][8 * 512];
    __shared__ __align__(16) unsigned short Al[2][8 * 512];
    __shared__ __align__(16) unsigned short Bh[2][8 * 512];
    __shared__ __align__(16) unsigned short Bl[2][8 * 512];

    const int t = threadIdx.x, lane = t & 63, wave = t >> 6;
    const int wm = wave >> 1, wn = wave & 1;
    const int gdec = (int)blockIdx.x >> 3, xs = (int)blockIdx.x & 7;
    const int cbk = gdec & 1;
    const int m0 = (((gdec >> 1) << 3) + xs) * 128;
    const int co0 = cbk * 128;
    const int lr = lane & 15, lc = lane >> 4;

    size_t a0 = (size_t)(m0 + wave * 16 + lr) * 256 + lc * 8;
    size_t a1 = a0 + 64 * 256;
    size_t b0 = (size_t)(co0 + wave * 16 + lr) * 256 + lc * 8;
    size_t b1 = b0 + 64 * 256;

    v4f acc[4][4];
#pragma unroll
    for (int i = 0; i < 4; i++)
#pragma unroll
        for (int j = 0; j < 4; j++)
#pragma unroll
            for (int r = 0; r < 4; r++) acc[i][j][r] = 0.f;

    auto do_stage = [&](int ci0, int pb) {
        gl_lds16(zh + a0 + ci0, &Ah[pb][wave * 512]);
        gl_lds16(zh + a1 + ci0, &Ah[pb][(wave + 4) * 512]);
        gl_lds16(zl + a0 + ci0, &Al[pb][wave * 512]);
        gl_lds16(zl + a1 + ci0, &Al[pb][(wave + 4) * 512]);
        gl_lds16(chb + b0 + ci0, &Bh[pb][wave * 512]);
        gl_lds16(chb + b1 + ci0, &Bh[pb][(wave + 4) * 512]);
        gl_lds16(clb + b0 + ci0, &Bl[pb][wave * 512]);
        gl_lds16(clb + b1 + ci0, &Bl[pb][(wave + 4) * 512]);
    };

    do_stage(0, 0);
    __syncthreads();

    for (int s = 0; s < 8; ++s) {
        const int pb = s & 1;
        if (s < 7) do_stage((s + 1) * 32, pb ^ 1);

        v8s a_h[4], a_l[4], b_h[4], b_l[4];
#pragma unroll
        for (int i = 0; i < 4; i++) {
            a_h[i] = *(const v8s*)&Ah[pb][(wm * 4 + i) * 512 + lane * 8];
            a_l[i] = *(const v8s*)&Al[pb][(wm * 4 + i) * 512 + lane * 8];
        }
#pragma unroll
        for (int j = 0; j < 4; j++) {
            b_h[j] = *(const v8s*)&Bh[pb][(wn * 4 + j) * 512 + lane * 8];
            b_l[j] = *(const v8s*)&Bl[pb][(wn * 4 + j) * 512 + lane * 8];
        }
#pragma unroll
        for (int i = 0; i < 4; i++)
#pragma unroll
            for (int j = 0; j < 4; j++) {
                acc[i][j] = __builtin_amdgcn_mfma_f32_16x16x32_bf16(a_h[i], b_h[j], acc[i][j], 0, 0, 0);
                acc[i][j] = __builtin_amdgcn_mfma_f32_16x16x32_bf16(a_h[i], b_l[j], acc[i][j], 0, 0, 0);
                acc[i][j] = __builtin_amdgcn_mfma_f32_16x16x32_bf16(a_l[i], b_h[j], acc[i][j], 0, 0, 0);
            }
        __syncthreads();
    }

#pragma unroll
    for (int i = 0; i < 4; i++) {
#pragma unroll
        for (int r = 0; r < 4; r++) {
            float best = 3.4e38f;
            int bi = 0;
#pragma unroll
            for (int j = 0; j < 4; j++) {
                int col = co0 + wn * 64 + j * 16 + (lane & 15);
                float d = cn2[col] - 2.f * acc[i][j][r];
                if (d < best || (d == best && col < bi)) { best = d; bi = col; }
            }
#pragma unroll
            for (int off = 1; off < 16; off <<= 1) {
                float ov = __shfl_xor(best, off);
                int oi = __shfl_xor(bi, off);
                if (ov < best || (ov == best && oi < bi)) { best = ov; bi = oi; }
            }
            if ((lane & 15) == 0) {
                int row = m0 + wm * 64 + i * 16 + (lane >> 4) * 4 + r;
                valp[(size_t)row * 4 + cbk * 2 + wn] = best;
                idxp[(size_t)row * 4 + cbk * 2 + wn] = bi;
            }
        }
    }
}

// ---------------------------------------------------------------------------
// VQ stage 3+4 fused: per-row candidate combine + gather + loss.
// ---------------------------------------------------------------------------
__global__ __launch_bounds__(TPB) void vq_gather2(
    const unsigned short* __restrict__ zh, const unsigned short* __restrict__ zl,
    const float* __restrict__ cb, const float* __restrict__ valp,
    const int* __restrict__ idxp, unsigned short* __restrict__ hq,
    float* __restrict__ rowloss)
{
    int row = blockIdx.x * 4 + (threadIdx.x >> 6);
    int lane = threadIdx.x & 63;
    float best = valp[(size_t)row * 4];
    int j = idxp[(size_t)row * 4];
#pragma unroll
    for (int c = 1; c < 4; c++) {
        float v = valp[(size_t)row * 4 + c];
        if (v < best) { best = v; j = idxp[(size_t)row * 4 + c]; }
    }
    ushort4 hv = *(const ushort4*)(zh + (size_t)row * 256 + lane * 4);
    ushort4 lv = *(const ushort4*)(zl + (size_t)row * 256 + lane * 4);
    float4 cv = *(const float4*)(cb + (size_t)j * 256 + lane * 4);
    float z0 = us2f(hv.x) + us2f(lv.x);
    float z1 = us2f(hv.y) + us2f(lv.y);
    float z2 = us2f(hv.z) + us2f(lv.z);
    float z3 = us2f(hv.w) + us2f(lv.w);
    float d0 = z0 - cv.x, d1 = z1 - cv.y, d2 = z2 - cv.z, d3 = z3 - cv.w;
    float d = d0 * d0 + d1 * d1 + d2 * d2 + d3 * d3;
#pragma unroll
    for (int off = 1; off < 64; off <<= 1) d += __shfl_xor(d, off);
    if (lane == 0) rowloss[row] = d;
    ushort4 o;
    o.x = f2us(cv.x); o.y = f2us(cv.y); o.z = f2us(cv.z); o.w = f2us(cv.w);
    *(ushort4*)(hq + (size_t)row * 256 + lane * 4) = o;
}

// Single-kernel loss reduction.
__global__ __launch_bounds__(TPB) void loss_all(
    const float* __restrict__ rowloss, float* __restrict__ out2)
{
    int t = threadIdx.x;
    float v = 0.f;
    for (int i = t; i < 32768; i += TPB) v += rowloss[i];
#pragma unroll
    for (int off = 1; off < 64; off <<= 1) v += __shfl_xor(v, off);
    __shared__ float p[4];
    if ((t & 63) == 0) p[t >> 6] = v;
    __syncthreads();
    if (t == 0) {
        float m = (p[0] + p[1] + p[2] + p[3]) * (1.0f / 32768.0f);
        out2[0] = m;
        out2[1] = m;
    }
}

// ---------------------------------------------------------------------------
// Decoder L4: MFMA + FUSED BN(g3)+ReLU in the reg-staging.
// ---------------------------------------------------------------------------
__global__ __launch_bounds__(TPB) void conv_d4(
    const unsigned short* __restrict__ xb, const unsigned short* __restrict__ wrep,
    const float* __restrict__ st, const float* __restrict__ gg,
    const float* __restrict__ be, const float* __restrict__ bias,
    float* __restrict__ out, int N)
{
    __shared__ __align__(16) unsigned short xsm[8 * 409 * 8];   // 52.4 KB
    __shared__ float scs[64], shs[64];
    int4* xsI = (int4*)xsm;
    const int t = threadIdx.x;
    const int lane = t & 63, wave = t >> 6;
    const int lr = lane & 15, lc = lane >> 4;

    if (t < 64) {
        float cnt = (float)(N * 4096);
        float m = st[t] / cnt;
        float vv = st[64 + t] / cnt - m * m;
        float s = gg[t] * rsqrtf(vv + 1e-5f);
        scs[t] = s;
        shs[t] = be[t] - m * s;
    }
    __syncthreads();

    const int n = blockIdx.x >> 4;
    const int tile = blockIdx.x & 15;
    const int th = tile >> 2, tw = tile & 3;
    const int ihh0 = 8 * th - 1, iwh0 = 8 * tw - 1;

    for (int s = t; s < 3200; s += TPB) {
        int cls = s / 800;
        int rem = s % 800;
        int ihh_l = rem / 80;
        int i4 = rem % 80;
        int iwh_l = i4 >> 3, c8 = i4 & 7;
        int ihh_g = ihh0 + ihh_l;
        int iwh_g = iwh0 + iwh_l;
        int4 v;
        if ((unsigned)ihh_g < 32u && (unsigned)iwh_g < 32u) {
            size_t row = (((size_t)cls * 128 + n) * 32 + ihh_g) * 32 + iwh_g;
            v = *(const int4*)(xb + row * 64 + c8 * 8);
            unsigned int* vu = (unsigned int*)&v;
            int c0 = c8 * 8;
#pragma unroll
            for (int k = 0; k < 4; k++) {
                float f0 = fmaxf(us2f(vu[k] & 0xffffu) * scs[c0 + 2 * k] + shs[c0 + 2 * k], 0.f);
                float f1 = fmaxf(us2f(vu[k] >> 16) * scs[c0 + 2 * k + 1] + shs[c0 + 2 * k + 1], 0.f);
                vu[k] = (unsigned int)f2us(f0) | ((unsigned int)f2us(f1) << 16);
            }
        } else {
            v.x = v.y = v.z = v.w = 0;
        }
        xsI[c8 * 409 + cls * 102 + ihh_l * 10 + iwh_l] = v;
    }
    __syncthreads();

    int abase[4][9];
#pragma unroll
    for (int q = 0; q < 4; q++) {
        int seg = wave * 4 + q;
        int oh = th * 16 + seg;
        int ow = tw * 16 + lr;
#pragma unroll
        for (int tap = 0; tap < 9; tap++) {
            int kh = tap / 3, kw = tap % 3;
            int ih = oh - 1 + kh, iw = ow - 1 + kw;
            int clsi = ((ih & 1) << 1) | (iw & 1);
            abase[q][tap] = clsi * 102 + ((ih >> 1) - ihh0) * 10 + ((iw >> 1) - iwh0);
        }
    }

    v4f acc[4];
#pragma unroll
    for (int q = 0; q < 4; q++)
#pragma unroll
        for (int r = 0; r < 4; r++) acc[q][r] = 0.f;

#pragma unroll
    for (int kk = 0; kk < 18; kk++) {
        const int tap = kk >> 1, half = kk & 1;
        const int c8 = half * 4 + lc;
        v8s b = *(const v8s*)(wrep + kk * 512 + lane * 8);
#pragma unroll
        for (int q = 0; q < 4; q++) {
            v8s a = *(const v8s*)&xsI[c8 * 409 + abase[q][tap]];
            acc[q] = __builtin_amdgcn_mfma_f32_16x16x32_bf16(a, b, acc[q], 0, 0, 0);
        }
    }

    if (lr < 3) {
        float bs = bias[lr];
#pragma unroll
        for (int q = 0; q < 4; q++) {
            int seg = wave * 4 + q;
            int oh = th * 16 + seg;
            int ow0 = tw * 16 + lc * 4;
            float4 v;
            v.x = acc[q][0] + bs; v.y = acc[q][1] + bs;
            v.z = acc[q][2] + bs; v.w = acc[q][3] + bs;
            *(float4*)&out[((size_t)n * 3 + lr) * 4096 + oh * 64 + ow0] = v;
        }
    }
}

// ---------------------------------------------------------------------------

extern "C" void kernel_launch(void* const* d_in, const int* in_sizes, int n_in,
                              void* d_out, int out_size, void* d_ws, size_t ws_size,
                              hipStream_t stream) {
    const float* x    = (const float*)d_in[0];
    const float* cb   = (const float*)d_in[1];
    const float* e_w1 = (const float*)d_in[2];  const float* e_b1 = (const float*)d_in[3];
    const float* e_g1 = (const float*)d_in[4];  const float* e_be1 = (const float*)d_in[5];
    const float* e_w2 = (const float*)d_in[6];  const float* e_b2 = (const float*)d_in[7];
    const float* e_g2 = (const float*)d_in[8];  const float* e_be2 = (const float*)d_in[9];
    const float* e_w3 = (const float*)d_in[10]; const float* e_b3 = (const float*)d_in[11];
    const float* e_g3 = (const float*)d_in[12]; const float* e_be3 = (const float*)d_in[13];
    const float* e_w4 = (const float*)d_in[14]; const float* e_b4 = (const float*)d_in[15];
    const float* d_w1 = (const float*)d_in[16]; const float* d_b1 = (const float*)d_in[17];
    const float* d_g1 = (const float*)d_in[18]; const float* d_be1 = (const float*)d_in[19];
    const float* d_w2 = (const float*)d_in[20]; const float* d_b2 = (const float*)d_in[21];
    const float* d_g2 = (const float*)d_in[22]; const float* d_be2 = (const float*)d_in[23];
    const float* d_w3 = (const float*)d_in[24]; const float* d_b3 = (const float*)d_in[25];
    const float* d_g3 = (const float*)d_in[26]; const float* d_be3 = (const float*)d_in[27];
    const float* d_w4 = (const float*)d_in[28]; const float* d_b4 = (const float*)d_in[29];

    float* ws = (float*)d_ws;
    unsigned short* h1 = (unsigned short*)(ws);              // class-major after E1
    unsigned short* g3 = h1;                                 // class-major after D3 (pre-BN)
    unsigned short* h2 = (unsigned short*)(ws + 16777216);   // [.., 25165824)
    unsigned short* g2 = h2;                                 // class-major after D2
    unsigned short* h3 = (unsigned short*)(ws + 25165824);   // [.., 28311552)
    unsigned short* g1 = h3;
    unsigned short* zh = (unsigned short*)(ws + 28311552);   // 8.4M shorts
    unsigned short* zl = (unsigned short*)(ws + 32505856);   // 8.4M shorts
    unsigned short* hq = (unsigned short*)(ws + 36700160);   // [.., 40894464)
    float* stats = ws + 40960000;                            // 3072
    unsigned short* we1 = (unsigned short*)(ws + 40963072);  // 2048 shorts
    unsigned short* wd4r = (unsigned short*)(ws + 40964096); // 9216 shorts
    float* cn2 = ws + 40995904;                              // 256
    unsigned short* chb = (unsigned short*)(ws + 40996160);  // 65536 shorts
    unsigned short* clb = (unsigned short*)(ws + 41028928);  // 65536 shorts
    unsigned short* wrep = (unsigned short*)(ws + 41061696);
    unsigned short* we2 = wrep + 0;        // 16*128*64   = 131072 (fragment-major)
    unsigned short* we3 = wrep + 131072;   // 16*192*128  = 393216
    unsigned short* we4 = wrep + 524288;   // 256*192     = 49152
    unsigned short* wd1 = wrep + 573440;   // 192*256     = 49152
    unsigned short* wd2 = wrep + 622592;   // 4*4*128*192 = 393216
    unsigned short* wd3 = wrep + 1015808;  // 4*4*64*128  = 131072
    float* part = ws + 41635136;           // BN partials / VQ candidates (8.4M floats)
    float* valp = part;                    // 131072 floats (dead outside VQ window)
    int* idxp = (int*)(part + 131072);     // 131072 ints
    float* rowloss = ws + 50023744;                          // 32768
    unsigned short* zpage = (unsigned short*)(ws + 50122112); // 256 B of zeros
    float* out = (float*)d_out;
    float* losses = out + 1572864;

    const int N = 128;

    // ---- all weight repacks + codebook prep (2 launches total) ----
    repack_all<<<4525, TPB, 0, stream>>>(
        e_w1, d_w4, e_w2, e_w3, e_w4, d_w1, d_w2, d_w3,
        we1, wd4r, we2, we3, we4, wd1, wd2, wd3, zpage);
    cb_prep<<<256, TPB, 0, stream>>>(cb, chb, clb, cn2);

    // ---- E1: 3->64 k3 s1 p1, FUSED im2col+MFMA GEMM -> CLASS-MAJOR h1 ----
    e1_gemm<<<4096, TPB, 0, stream>>>(x, we1, e_b1, h1, part, N);
    bn_reduce2<64><<<128, 64, 0, stream>>>(part, stats + 0 * 512, 4096);
    bn_apply_v<64><<<4096, TPB, 0, stream>>>(h1, stats + 0 * 512, e_g1, e_be1, 524288);

    // ---- E2: 64->128 k4 s2 p1, class-major input, contiguous DMA ----
    conv_c<64, 128, 32, 32, 2>
        <<<1024, TPB, 0, stream>>>(h1, we2, e_b2, h2, part, zpage, N);
    bn_reduce2<128><<<256, 64, 0, stream>>>(part, stats + 1 * 512, 512);
    bn_apply_v<128><<<2048, TPB, 0, stream>>>(h2, stats + 1 * 512, e_g2, e_be2, 131072);

    // ---- E3: 128->192 k4 s2 p1 (MFMA BK=64, dbuf, fused stats, XCD-aware) ----
    conv_mfma<128, 192, 32, 32, 4, 2, 1, 96, 0, 2>
        <<<512, TPB, 0, stream>>>(h2, we3, e_b3, h3, nullptr, part, zpage, N);
    bn_reduce2<192><<<384, 64, 0, stream>>>(part, stats + 2 * 512, 256);
    bn_apply_v<192><<<1024, TPB, 0, stream>>>(h3, stats + 2 * 512, e_g3, e_be3, 32768);

    // ---- E4: 192->256 1x1 (MFMA BK=64, dbuf, hi/lo split out for VQ) ----
    conv_mfma<192, 256, 16, 16, 1, 1, 0, 128, 2, 2>
        <<<512, TPB, 0, stream>>>(h3, we4, e_b4, zh, zl, nullptr, zpage, N);

    // ---- VQ: fused GEMM+argmin -> gather(with combine) -> loss ----
    vq_gemm<<<512, TPB, 0, stream>>>(zh, zl, chb, clb, cn2, valp, idxp);
    vq_gather2<<<8192, TPB, 0, stream>>>(zh, zl, cb, valp, idxp, hq, rowloss);
    loss_all<<<1, TPB, 0, stream>>>(rowloss, losses);

    // ---- D1: 256->192 1x1 convT (MFMA BK=64, dbuf, fused stats, XCD-aware) ----
    conv_mfma<256, 192, 16, 16, 1, 1, 0, 96, 0, 2>
        <<<512, TPB, 0, stream>>>(hq, wd1, d_b1, g1, nullptr, part, zpage, N);
    bn_reduce2<192><<<384, 64, 0, stream>>>(part, stats + 3 * 512, 256);
    bn_apply_v<192><<<1024, TPB, 0, stream>>>(g1, stats + 3 * 512, d_g1, d_be1, 32768);

    // ---- D2: 192->128 convT, contiguous-DMA dbuf (NHWC in, cls-major out) ----
    convt_c<192, 128, 16, 16, 2, 0>
        <<<1024, TPB, 0, stream>>>(g1, wd2, d_b2, g2, part, zpage, N);
    bn_reduce2<128><<<256, 64, 0, stream>>>(part, stats + 4 * 512, 512);
    bn_apply_v<128><<<2048, TPB, 0, stream>>>(g2, stats + 4 * 512, d_g2, d_be2, 131072);

    // ---- D3: 128->64 convT, barrier-free 1-buf + precomputed addresses ----
    convt_nb<128, 64, 32, 32, 1>
        <<<2048, TPB, 0, stream>>>(g2, wd3, d_b3, g3, part, zpage, N);
    bn_reduce2<64><<<128, 64, 0, stream>>>(part, stats + 5 * 512, 2048);
    // bn_apply for g3 FUSED into conv_d4 staging (sole consumer).

    // ---- D4: 64->3 k3 s1 p1 (MFMA, fused BN+ReLU staging) -> NCHW fp32 ----
    conv_d4<<<2048, TPB, 0, stream>>>(g3, wd4r, stats + 5 * 512, d_g3, d_be3,
                                      d_b4, out, N);
}

// Round 17
// 561.226 us; speedup vs baseline: 1.0094x; 1.0094x over previous
//
#include <hip/hip_runtime.h>

#define TPB 256

typedef __attribute__((ext_vector_type(4))) float v4f;
typedef __attribute__((ext_vector_type(8))) short v8s;

__device__ __forceinline__ float us2f(unsigned int u) {
    union { unsigned int i; float f; } w; w.i = u << 16; return w.f;
}
__device__ __forceinline__ unsigned short f2us(float f) {
    union { float ff; unsigned int i; } w; w.ff = f;
    unsigned int u = w.i;
    return (unsigned short)((u + 0x7fffu + ((u >> 16) & 1u)) >> 16);
}
// Async global->LDS DMA, 16 B per lane. LDS dest = wave-uniform base + lane*16.
// NOTE: the GLOBAL source is PER-LANE — each lane loads 16 B from its own g.
__device__ __forceinline__ void gl_lds16(const unsigned short* g, unsigned short* l) {
    __builtin_amdgcn_global_load_lds(
        (const __attribute__((address_space(1))) unsigned int*)g,
        (__attribute__((address_space(3))) unsigned int*)l, 16, 0, 0);
}

// ---------------------------------------------------------------------------
// MERGED weight repack: all 8 repacks + zpage zeroing in ONE kernel.
// zpage is 512 B (256 shorts) so OOB DMA sources at zpage + cc*128B (cc<=2)
// stay inside the zero page.
// ---------------------------------------------------------------------------
__global__ __launch_bounds__(TPB) void repack_all(
    const float* __restrict__ e_w1, const float* __restrict__ d_w4,
    const float* __restrict__ e_w2, const float* __restrict__ e_w3,
    const float* __restrict__ e_w4, const float* __restrict__ d_w1,
    const float* __restrict__ d_w2, const float* __restrict__ d_w3,
    unsigned short* __restrict__ we1, unsigned short* __restrict__ wd4r,
    unsigned short* __restrict__ we2, unsigned short* __restrict__ we3,
    unsigned short* __restrict__ we4, unsigned short* __restrict__ wd1,
    unsigned short* __restrict__ wd2, unsigned short* __restrict__ wd3,
    unsigned short* __restrict__ zpage)
{
    int gid = blockIdx.x * TPB + threadIdx.x;
    if (gid < 2048) {
        int idx = gid;
        int k = idx & 31, co = idx >> 5;
        we1[idx] = (k < 27) ? f2us(e_w1[co * 27 + k]) : (unsigned short)0;
        return;
    }
    gid -= 2048;
    if (gid < 9216) {
        int idx = gid;
        int e = idx & 7;
        int lane = (idx >> 3) & 63;
        int kk = idx >> 9;
        int lr = lane & 15, lc = lane >> 4;
        int tap = kk >> 1, half = kk & 1;
        int ci = half * 32 + lc * 8 + e;
        wd4r[idx] = (lr < 3) ? f2us(d_w4[((size_t)lr * 64 + ci) * 9 + tap])
                             : (unsigned short)0;
        return;
    }
    gid -= 9216;
    if (gid < 131072) {
        int idx = gid;
        int e = idx & 7;
        int lane = (idx >> 3) & 63;
        int seg8 = (idx >> 9) & 7;
        int u = idx >> 12;
        int cb = u % 2, tap = u / 2;
        int lr = lane & 15, lc = lane >> 4;
        int kc = seg8 >> 2, sg = seg8 & 3;
        int co = cb * 64 + sg * 16 + lr;
        int ci = kc * 32 + lc * 8 + e;
        we2[idx] = f2us(e_w2[((size_t)co * 64 + ci) * 16 + tap]);
        return;
    }
    gid -= 131072;
    if (gid < 393216) {
        int idx = gid;
        int ci = idx % 128;
        int co = (idx / 128) % 192;
        int kk = idx / (128 * 192);
        we3[idx] = f2us(e_w3[((size_t)co * 128 + ci) * 16 + kk]);
        return;
    }
    gid -= 393216;
    if (gid < 49152) {
        int idx = gid;
        int ci = idx % 192;
        int co = (idx / 192) % 256;
        we4[idx] = f2us(e_w4[(size_t)co * 192 + ci]);
        return;
    }
    gid -= 49152;
    if (gid < 49152) {
        int idx = gid;
        int ci = idx % 256;
        int co = idx / 256;
        wd1[idx] = f2us(d_w1[(size_t)ci * 192 + co]);
        return;
    }
    gid -= 49152;
    if (gid < 393216) {
        int idx = gid;
        int e = idx & 7;
        int lane = (idx >> 3) & 63;
        int seg8 = (idx >> 9) & 7;
        int u = idx >> 12;
        int cb = u % 2;
        int u2 = u / 2;
        int cc = u2 % 3;
        int tk = u2 / 3;
        int kidx = tk & 3, cls = tk >> 2;
        int lr = lane & 15, lc = lane >> 4;
        int kc = seg8 >> 2, sg = seg8 & 3;
        int co = cb * 64 + sg * 16 + lr;
        int ci = cc * 64 + kc * 32 + lc * 8 + e;
        int ohp = cls >> 1, owp = cls & 1;
        int kh = ((ohp + 1) & 1) + 2 * (kidx >> 1);
        int kw = ((owp + 1) & 1) + 2 * (kidx & 1);
        wd2[idx] = f2us(d_w2[((size_t)ci * 128 + co) * 16 + kh * 4 + kw]);
        return;
    }
    gid -= 393216;
    if (gid < 131072) {
        int idx = gid;
        int e = idx & 7;
        int lane = (idx >> 3) & 63;
        int seg8 = (idx >> 9) & 7;
        int u2 = idx >> 12;
        int cc = u2 % 2;
        int tk = u2 / 2;
        int kidx = tk & 3, cls = tk >> 2;
        int lr = lane & 15, lc = lane >> 4;
        int kc = seg8 >> 2, sg = seg8 & 3;
        int co = sg * 16 + lr;
        int ci = cc * 64 + kc * 32 + lc * 8 + e;
        int ohp = cls >> 1, owp = cls & 1;
        int kh = ((ohp + 1) & 1) + 2 * (kidx >> 1);
        int kw = ((owp + 1) & 1) + 2 * (kidx & 1);
        wd3[idx] = f2us(d_w3[((size_t)ci * 64 + co) * 16 + kh * 4 + kw]);
        return;
    }
    gid -= 131072;
    if (gid < 256) zpage[gid] = 0;
}

// ---------------------------------------------------------------------------
// E1: FUSED im2col + MFMA GEMM. Output CLASS-MAJOR; fused BN partials.
// ---------------------------------------------------------------------------
__global__ __launch_bounds__(TPB) void e1_gemm(
    const float* __restrict__ x, const unsigned short* __restrict__ wrep,
    const float* __restrict__ bias, unsigned short* __restrict__ yout,
    float* __restrict__ part, int N)
{
    __shared__ __align__(16) unsigned short Ab[8 * 512];   // 8 KB
    __shared__ __align__(16) unsigned short Bb[4 * 512];   // 4 KB

    const int t = threadIdx.x, lane = t & 63, wave = t >> 6;
    const int wm = wave >> 1, wn = wave & 1;
    const int m0 = (int)blockIdx.x * 128;
    const int lr = lane & 15, lc = lane >> 4;

    gl_lds16(wrep + (size_t)(wave * 16 + lr) * 32 + lc * 8, &Bb[wave * 512]);

    {
        int r = m0 + (t >> 1);
        int h = t & 1;
        int n = r >> 12, oh = (r >> 6) & 63, ow = r & 63;
        unsigned short rowv[16];
#pragma unroll
        for (int kk = 0; kk < 16; kk++) {
            int k = h * 16 + kk;
            float v = 0.f;
            if (k < 27) {
                int ci = k / 9, tap = k % 9, kh = tap / 3, kw = tap % 3;
                int ih = oh - 1 + kh, iw = ow - 1 + kw;
                if ((unsigned)ih < 64u && (unsigned)iw < 64u)
                    v = x[(((size_t)n * 3 + ci) * 64 + ih) * 64 + iw];
            }
            rowv[kk] = f2us(v);
        }
        int rl = (t >> 1) & 15;
        int s = (t >> 1) >> 4;
        int base = s * 512 + (h * 32 + rl) * 8;   // shorts
        *(int4*)&Ab[base] = *(const int4*)&rowv[0];
        *(int4*)&Ab[base + 128] = *(const int4*)&rowv[8];
    }
    __syncthreads();

    v4f acc[4][2];
#pragma unroll
    for (int i = 0; i < 4; i++)
#pragma unroll
        for (int j = 0; j < 2; j++)
#pragma unroll
            for (int r = 0; r < 4; r++) acc[i][j][r] = 0.f;

    v8s a[4], b[2];
#pragma unroll
    for (int i = 0; i < 4; i++)
        a[i] = *(const v8s*)&Ab[(wm * 4 + i) * 512 + lane * 8];
#pragma unroll
    for (int j = 0; j < 2; j++)
        b[j] = *(const v8s*)&Bb[(wn * 2 + j) * 512 + lane * 8];
#pragma unroll
    for (int i = 0; i < 4; i++)
#pragma unroll
        for (int j = 0; j < 2; j++)
            acc[i][j] = __builtin_amdgcn_mfma_f32_16x16x32_bf16(a[i], b[j], acc[i][j], 0, 0, 0);

    float sloc[2], qloc[2];
#pragma unroll
    for (int j = 0; j < 2; j++) { sloc[j] = 0.f; qloc[j] = 0.f; }

#pragma unroll
    for (int i = 0; i < 4; i++) {
        int mr = wm * 64 + i * 16 + (lane >> 4) * 4;
#pragma unroll
        for (int j = 0; j < 2; j++) {
            int col = wn * 32 + j * 16 + (lane & 15);
            float bs = bias[col];
#pragma unroll
            for (int r = 0; r < 4; r++) {
                int row = m0 + mr + r;
                int n = row >> 12, oh = (row >> 6) & 63, ow = row & 63;
                int cls = ((oh & 1) << 1) | (ow & 1);
                size_t crow = ((((size_t)cls * N + n) * 32 + (oh >> 1)) * 32 + (ow >> 1));
                float v = acc[i][j][r] + bs;
                yout[crow * 64 + col] = f2us(v);
                sloc[j] += v;
                qloc[j] += v * v;
            }
        }
    }

    __syncthreads();
    float* red = (float*)Ab;
    for (int i = t; i < 128; i += TPB) red[i] = 0.f;
    __syncthreads();
#pragma unroll
    for (int j = 0; j < 2; j++) {
        float s = sloc[j], qv = qloc[j];
        s += __shfl_xor(s, 16); s += __shfl_xor(s, 32);
        qv += __shfl_xor(qv, 16); qv += __shfl_xor(qv, 32);
        if ((lane >> 4) == 0) {
            int cl = wn * 32 + j * 16 + (lane & 15);
            atomicAdd(&red[cl], s);
            atomicAdd(&red[64 + cl], qv);
        }
    }
    __syncthreads();
    int PB = (int)gridDim.x, pb = (int)blockIdx.x;
    for (int i = t; i < 64; i += TPB) {
        part[(size_t)i * PB + pb] = red[i];
        part[(size_t)(64 + i) * PB + pb] = red[64 + i];
    }
}

// ---------------------------------------------------------------------------
// Forward conv k4 s2 p1 with CLASS-MAJOR input, contiguous-DMA staging (E2).
// ---------------------------------------------------------------------------
template<int CIN, int COUT, int HO, int WO, int NCB>
__global__ __launch_bounds__(TPB) void conv_c(
    const unsigned short* __restrict__ xin, const unsigned short* __restrict__ wrep,
    const float* __restrict__ bias, unsigned short* __restrict__ yout,
    float* __restrict__ part, const unsigned short* __restrict__ zpage, int N)
{
    constexpr int NCI = CIN / 64;
    constexpr int NIT = 16 * NCI;
    __shared__ __align__(16) unsigned short Ab[2][16 * 1024];  // 64 KB
    __shared__ __align__(16) unsigned short Bb[2][8 * 512];    // 16 KB

    const int t = threadIdx.x, lane = t & 63, wave = t >> 6;
    int gdec = (int)blockIdx.x >> 3, xs = (int)blockIdx.x & 7;
    int cb = 0;
    if (NCB >= 2) { cb = gdec % NCB; gdec /= NCB; }
    const int tile = (gdec << 3) + xs;
    const int m0 = tile * 256;
    const int co0 = cb * 64;
    const int lr = lane & 15, lc = lane >> 4;

    const int jr7 = lane >> 3;
    const int sw = ((lane & 7) ^ jr7) * 8;   // shorts

    int n_[4], oh_[4], ow0_[4];
#pragma unroll
    for (int q = 0; q < 4; q++) {
        int r0 = m0 + (wave * 4 + q) * 16;
        n_[q] = r0 / (HO * WO);
        int rem = r0 % (HO * WO);
        oh_[q] = rem / WO;
        ow0_[q] = rem % WO;
    }

    v4f acc[4][4];
#pragma unroll
    for (int i = 0; i < 4; i++)
#pragma unroll
        for (int j = 0; j < 4; j++)
#pragma unroll
            for (int r = 0; r < 4; r++) acc[i][j][r] = 0.f;

    auto stage = [&](int it, int buf) {
        const int tap = it / NCI, cc = it % NCI;
        const int kh = tap >> 2, kw = tap & 3;
        const int dcls = (((kh + 1) & 1) << 1) | ((kw + 1) & 1);
        const int dh2 = (kh - 1) >> 1;
        const int dw2 = (kw - 1) >> 1;
#pragma unroll
        for (int q = 0; q < 4; q++) {
            const int ih2 = oh_[q] + dh2;
            const bool ihv = (unsigned)ih2 < (unsigned)HO;
#pragma unroll
            for (int h = 0; h < 2; h++) {
                int iw2 = ow0_[q] + h * 8 + jr7 + dw2;
                bool av = ihv && (unsigned)iw2 < (unsigned)WO;
                size_t ab = ((((size_t)dcls * N + n_[q]) * HO + ih2) * WO + iw2) * CIN;
                const unsigned short* src = av ? xin + ab + cc * 64 + sw : zpage;
                gl_lds16(src, &Ab[buf][(wave * 4 + q) * 1024 + h * 512]);
            }
        }
        const unsigned short* wb = wrep
            + ((size_t)(tap * NCI + cc) * NCB + cb) * 4096;
        gl_lds16(wb + wave * 512 + lane * 8, &Bb[buf][wave * 512]);
        gl_lds16(wb + (4 + wave) * 512 + lane * 8, &Bb[buf][(4 + wave) * 512]);
    };

    auto compute = [&](int it, int buf) {
#pragma unroll
        for (int kc = 0; kc < 2; kc++) {
            v8s a[4], b[4];
#pragma unroll
            for (int i = 0; i < 4; i++)
                a[i] = *(const v8s*)&Ab[buf][(wave * 4 + i) * 1024 + lr * 64
                        + ((kc * 32 + lc * 8) ^ ((lr & 7) << 3))];
#pragma unroll
            for (int j = 0; j < 4; j++)
                b[j] = *(const v8s*)&Bb[buf][(kc * 4 + j) * 512 + lane * 8];
#pragma unroll
            for (int i = 0; i < 4; i++)
#pragma unroll
                for (int j = 0; j < 4; j++)
                    acc[i][j] = __builtin_amdgcn_mfma_f32_16x16x32_bf16(a[i], b[j], acc[i][j], 0, 0, 0);
        }
    };

    stage(0, 0);
    __syncthreads();

#pragma unroll
    for (int it = 0; it < NIT; ++it) {
        const int buf = it & 1;
        if (it + 1 < NIT) stage(it + 1, buf ^ 1);
        compute(it, buf);
        __syncthreads();
    }

    float sloc[4], qloc[4];
#pragma unroll
    for (int j = 0; j < 4; j++) { sloc[j] = 0.f; qloc[j] = 0.f; }

#pragma unroll
    for (int i = 0; i < 4; i++) {
        int mr = wave * 64 + i * 16 + (lane >> 4) * 4;
#pragma unroll
        for (int j = 0; j < 4; j++) {
            int col = co0 + j * 16 + (lane & 15);
            float bs = bias[col];
#pragma unroll
            for (int r = 0; r < 4; r++) {
                size_t gi = (size_t)(m0 + mr + r) * COUT + col;
                float v = acc[i][j][r] + bs;
                yout[gi] = f2us(v);
                sloc[j] += v;
                qloc[j] += v * v;
            }
        }
    }

    float* red = (float*)Ab;
    for (int i = t; i < 128; i += TPB) red[i] = 0.f;
    __syncthreads();
#pragma unroll
    for (int j = 0; j < 4; j++) {
        float s = sloc[j], qv = qloc[j];
        s += __shfl_xor(s, 16); s += __shfl_xor(s, 32);
        qv += __shfl_xor(qv, 16); qv += __shfl_xor(qv, 32);
        if ((lane >> 4) == 0) {
            int cl = j * 16 + (lane & 15);
            atomicAdd(&red[cl], s);
            atomicAdd(&red[64 + cl], qv);
        }
    }
    __syncthreads();
    const int TILES = (N * HO * WO) >> 8;
    const int pb = tile;
    for (int i = t; i < 64; i += TPB) {
        part[(size_t)(co0 + i) * TILES + pb] = red[i];
        part[(size_t)(COUT + co0 + i) * TILES + pb] = red[64 + i];
    }
}

// ---------------------------------------------------------------------------
// MFMA implicit-GEMM conv, DMA-staged (scattered), BK=64 — E3 / E4 / D1.
// ---------------------------------------------------------------------------
template<int CIN, int COUT, int HIN, int WIN, int K, int S, int P, int BN,
         int OUTM, int NYB>
__global__ __launch_bounds__(TPB) void conv_mfma(
    const unsigned short* __restrict__ xin, const unsigned short* __restrict__ wrep,
    const float* __restrict__ bias, void* __restrict__ yout, void* __restrict__ yout2,
    float* __restrict__ part, const unsigned short* __restrict__ zpage, int N)
{
    constexpr int HOUT = (HIN + 2 * P - K) / S + 1;
    constexpr int WOUT = (WIN + 2 * P - K) / S + 1;
    constexpr int RN = BN / 32;
    constexpr int BSEG = BN / 16;
    constexpr int NCI = CIN / 64;
    constexpr int NIT = K * K * NCI;
    __shared__ __align__(16) unsigned short Ab[2][16 * 512];
    __shared__ __align__(16) unsigned short Bb[2][2 * BSEG * 512];

    const int t = threadIdx.x, lane = t & 63, wave = t >> 6;
    const int wm = wave >> 1, wn = wave & 1;
    int m0, co0;
    if (NYB == 2) {
        int g = (int)blockIdx.x >> 3, xs = (int)blockIdx.x & 7;
        co0 = (g & 1) * BN;
        m0 = (((g >> 1) << 3) + xs) * 128;
    } else {
        m0 = (int)blockIdx.x * 128;
        co0 = 0;
    }
    const int lr = lane & 15, lc = lane >> 4;

    int n_[2], oh_[2], ow_[2];
#pragma unroll
    for (int i = 0; i < 2; i++) {
        int r = m0 + (wave + 4 * i) * 16 + lr;
        n_[i] = r / (HOUT * WOUT);
        int rem = r % (HOUT * WOUT);
        oh_[i] = rem / WOUT;
        ow_[i] = rem % WOUT;
    }

    v4f acc[4][RN];
#pragma unroll
    for (int i = 0; i < 4; i++)
#pragma unroll
        for (int j = 0; j < RN; j++)
#pragma unroll
            for (int r = 0; r < 4; r++) acc[i][j][r] = 0.f;

    auto do_stage = [&](int it, int pb) {
        const int kk = it / NCI;
        const int ci0 = (it % NCI) * 64;
        const int kh = kk / K, kw = kk % K;
#pragma unroll
        for (int i = 0; i < 2; i++) {
            int ih = oh_[i] * S - P + kh;
            int iw = ow_[i] * S - P + kw;
            bool av = (unsigned)ih < (unsigned)HIN && (unsigned)iw < (unsigned)WIN;
            const unsigned short* b0 = av
                ? xin + (((size_t)n_[i] * HIN + ih) * WIN + iw) * CIN + lc * 8 + ci0
                : zpage;
            gl_lds16(b0, &Ab[pb][(wave + 4 * i) * 512]);
            gl_lds16(av ? b0 + 32 : zpage, &Ab[pb][(8 + wave + 4 * i) * 512]);
        }
        const unsigned short* wt = wrep + (size_t)kk * COUT * CIN;
#pragma unroll
        for (int i = 0; i < 2; i++) {
            int sgb = wave + 4 * i;
            if (sgb < BSEG) {
                const unsigned short* wb =
                    wt + (size_t)(co0 + sgb * 16 + lr) * CIN + ci0 + lc * 8;
                gl_lds16(wb, &Bb[pb][sgb * 512]);
                gl_lds16(wb + 32, &Bb[pb][(BSEG + sgb) * 512]);
            }
        }
    };

    do_stage(0, 0);
    __syncthreads();

    for (int it = 0; it < NIT; ++it) {
        const int pb = it & 1;
        if (it + 1 < NIT) do_stage(it + 1, pb ^ 1);

#pragma unroll
        for (int kc = 0; kc < 2; kc++) {
            v8s a[4], b[RN];
#pragma unroll
            for (int i = 0; i < 4; i++)
                a[i] = *(const v8s*)&Ab[pb][(kc * 8 + wm * 4 + i) * 512 + lane * 8];
#pragma unroll
            for (int j = 0; j < RN; j++)
                b[j] = *(const v8s*)&Bb[pb][(kc * BSEG + wn * RN + j) * 512 + lane * 8];
#pragma unroll
            for (int i = 0; i < 4; i++)
#pragma unroll
                for (int j = 0; j < RN; j++)
                    acc[i][j] = __builtin_amdgcn_mfma_f32_16x16x32_bf16(a[i], b[j], acc[i][j], 0, 0, 0);
        }
        __syncthreads();
    }

    float sloc[RN], qloc[RN];
#pragma unroll
    for (int j = 0; j < RN; j++) { sloc[j] = 0.f; qloc[j] = 0.f; }

#pragma unroll
    for (int i = 0; i < 4; i++) {
        int mr = wm * 64 + i * 16 + (lane >> 4) * 4;
#pragma unroll
        for (int j = 0; j < RN; j++) {
            int col = co0 + wn * (BN / 2) + j * 16 + (lane & 15);
            float bs = bias[col];
#pragma unroll
            for (int r = 0; r < 4; r++) {
                size_t g = (size_t)(m0 + mr + r) * COUT + col;
                float v = acc[i][j][r] + bs;
                if (OUTM == 2) {
                    unsigned short h = f2us(v);
                    ((unsigned short*)yout)[g] = h;
                    ((unsigned short*)yout2)[g] = f2us(v - us2f(h));
                } else {
                    ((unsigned short*)yout)[g] = f2us(v);
                    sloc[j] += v;
                    qloc[j] += v * v;
                }
            }
        }
    }

    if (OUTM == 0) {
        __syncthreads();
        float* red = (float*)Ab;
        for (int i = t; i < 2 * BN; i += TPB) red[i] = 0.f;
        __syncthreads();
#pragma unroll
        for (int j = 0; j < RN; j++) {
            float s = sloc[j], qv = qloc[j];
            s += __shfl_xor(s, 16); s += __shfl_xor(s, 32);
            qv += __shfl_xor(qv, 16); qv += __shfl_xor(qv, 32);
            if ((lane >> 4) == 0) {
                int cl = wn * (BN / 2) + j * 16 + (lane & 15);
                atomicAdd(&red[cl], s);
                atomicAdd(&red[BN + cl], qv);
            }
        }
        __syncthreads();
        int pb = (NYB == 2) ? (m0 >> 7) : (int)blockIdx.x;
        int PB = (NYB == 2) ? ((int)gridDim.x >> 1) : (int)gridDim.x;
        for (int i = t; i < BN; i += TPB) {
            int col = co0 + i;
            part[(size_t)col * PB + pb] = red[i];
            part[(size_t)(COUT + col) * PB + pb] = red[BN + i];
        }
    }
}

// ---------------------------------------------------------------------------
// Transposed conv, BARRIER-FREE + DOUBLE-BUFFER + HOISTED ADDRESSES (v4) —
// D2 (NCB=2) and D3 (NCB=1). Wave-private A in 2x32-KB LDS; B in per-lane
// registers (bA/bB parity). 2-deep counted pipeline: pair(it) = 8 A-DMAs +
// 8 B-loads; vmcnt(16) at iter top retires pair(it) leaving pair(it+1) in
// flight (a full compute phase between issue and wait -> latency hidden).
// All 32 (q,tap,h) source offsets hoisted to int32 prologue (OOB -> zpage;
// +cc*128B stays inside the 512-B zero page). lgkmcnt(0)+sched_barrier
// guards the same-wave LDS WAR before re-staging.
// Same addresses/DMA order/MFMA order => bitwise-identical accumulation.
// ---------------------------------------------------------------------------
template<int CIN, int COUT, int HIN, int WIN, int NCB, int IN_CLS>
__global__ __launch_bounds__(TPB) void convt_nb(
    const unsigned short* __restrict__ xin, const unsigned short* __restrict__ wrep,
    const float* __restrict__ bias, unsigned short* __restrict__ yout,
    float* __restrict__ part, const unsigned short* __restrict__ zpage, int N)
{
    constexpr int NCI = CIN / 64;
    constexpr int NIT = 4 * NCI;
    __shared__ __align__(16) unsigned short Ab[2][16 * 1024];  // 64 KB dbuf
    __shared__ float red[128];

    const int t = threadIdx.x, lane = t & 63, wave = t >> 6;
    int gdec = (int)blockIdx.x >> 3, xs = (int)blockIdx.x & 7;
    int cb = 0;
    if (NCB == 2) { cb = gdec & 1; gdec >>= 1; }
    const int cls = gdec & 3;
    const int tile = ((gdec >> 2) << 3) + xs;
    const int m0 = tile * 256;
    const int co0 = cb * 64;
    const int ohp = cls >> 1, owp = cls & 1;
    const int khb = (ohp + 1) & 1, kwb = (owp + 1) & 1;
    const int dh0 = (ohp + 1 - khb) >> 1, dw0 = (owp + 1 - kwb) >> 1;
    const int lr = lane & 15, lc = lane >> 4;

    const int jr7 = lane >> 3;
    const int sw = ((lane & 7) ^ jr7) * 8;   // shorts

    int n_[4], i_[4], j0_[4];
#pragma unroll
    for (int q = 0; q < 4; q++) {
        int r0 = m0 + (wave * 4 + q) * 16;
        n_[q] = r0 / (HIN * WIN);
        int rem = r0 % (HIN * WIN);
        i_[q] = rem / WIN;
        j0_[q] = rem % WIN;
    }

    // hoisted per-lane byte offsets [q][tap][h] (int32; OOB -> zpage)
    int aoffb[4][4][2];
    {
        const int zdb = (int)((const char*)zpage - (const char*)xin);
#pragma unroll
        for (int q = 0; q < 4; q++) {
#pragma unroll
            for (int tap = 0; tap < 4; tap++) {
                const int dh = dh0 - (tap >> 1);
                const int dw = dw0 - (tap & 1);
                const int ih = i_[q] + dh;
                const bool ihv = (unsigned)ih < (unsigned)HIN;
#pragma unroll
                for (int h = 0; h < 2; h++) {
                    int iw = j0_[q] + h * 8 + jr7 + dw;
                    bool av = ihv && (unsigned)iw < (unsigned)WIN;
                    size_t ab;
                    if (IN_CLS) {
                        int clsi = ((ih & 1) << 1) | (iw & 1);
                        ab = ((((size_t)clsi * N + n_[q]) * (HIN / 2) + (ih >> 1)) * (WIN / 2)
                             + (iw >> 1)) * CIN;
                    } else {
                        ab = (((size_t)n_[q] * HIN + ih) * WIN + iw) * CIN;
                    }
                    aoffb[q][tap][h] = av ? (int)((ab + sw) * 2) : zdb;
                }
            }
        }
    }

    v4f acc[4][4];
#pragma unroll
    for (int i = 0; i < 4; i++)
#pragma unroll
        for (int j = 0; j < 4; j++)
#pragma unroll
            for (int r = 0; r < 4; r++) acc[i][j][r] = 0.f;

    // A staging: 8 DMAs from precomputed offsets (cc*128 B stays inside the
    // 512-B zero page on OOB lanes, so the add is unconditional)
    auto stageA = [&](int it, int buf) {
        const int tap = it / NCI, cc = it % NCI;
#pragma unroll
        for (int q = 0; q < 4; q++) {
#pragma unroll
            for (int h = 0; h < 2; h++) {
                const unsigned short* src = (const unsigned short*)
                    ((const char*)xin + aoffb[q][tap][h] + cc * 128);
                gl_lds16(src, &Ab[buf][(wave * 4 + q) * 1024 + h * 512]);
            }
        }
    };
    auto loadB = [&](int it, v8s (&breg)[8]) {
        const int tap = it / NCI, cc = it % NCI;
        const unsigned short* wb = wrep
            + ((size_t)((cls * 4 + tap) * NCI + cc) * NCB + cb) * 4096;
#pragma unroll
        for (int s = 0; s < 8; s++)
            breg[s] = *(const v8s*)(wb + s * 512 + lane * 8);
    };
    auto computeIt = [&](int buf, const v8s (&breg)[8]) {
#pragma unroll
        for (int kc = 0; kc < 2; kc++) {
            v8s a[4];
#pragma unroll
            for (int i = 0; i < 4; i++)
                a[i] = *(const v8s*)&Ab[buf][(wave * 4 + i) * 1024 + lr * 64
                        + ((kc * 32 + lc * 8) ^ ((lr & 7) << 3))];
#pragma unroll
            for (int i = 0; i < 4; i++)
#pragma unroll
                for (int j = 0; j < 4; j++)
                    acc[i][j] = __builtin_amdgcn_mfma_f32_16x16x32_bf16(a[i], breg[kc * 4 + j], acc[i][j], 0, 0, 0);
        }
    };

    v8s bA[8], bB[8];
    stageA(0, 0); loadB(0, bA);
    stageA(1, 1); loadB(1, bB);

#pragma unroll
    for (int it = 0; it < NIT; ++it) {
        const int buf = it & 1;
        // retire pair(it) = stageA(it)+loadB(it); leave pair(it+1) in flight
        if (it + 1 < NIT) { asm volatile("s_waitcnt vmcnt(16)" ::: "memory"); }
        else              { asm volatile("s_waitcnt vmcnt(0)" ::: "memory"); }
        __builtin_amdgcn_sched_barrier(0);
        if (buf == 0) computeIt(0, bA); else computeIt(1, bB);
        if (it + 2 < NIT) {
            // same-wave LDS WAR: all ds_reads of compute(it) retired first
            asm volatile("s_waitcnt lgkmcnt(0)" ::: "memory");
            __builtin_amdgcn_sched_barrier(0);
            stageA(it + 2, buf);
            if (buf == 0) loadB(it + 2, bA); else loadB(it + 2, bB);
        }
    }

    float sloc[4], qloc[4];
#pragma unroll
    for (int j = 0; j < 4; j++) { sloc[j] = 0.f; qloc[j] = 0.f; }

    const size_t clsbase = (size_t)cls * N * HIN * WIN;
#pragma unroll
    for (int i = 0; i < 4; i++) {
        int mr = wave * 64 + i * 16 + (lane >> 4) * 4;
#pragma unroll
        for (int j = 0; j < 4; j++) {
            int col = co0 + j * 16 + (lane & 15);
            float bs = bias[col];
#pragma unroll
            for (int r = 0; r < 4; r++) {
                size_t gi = (clsbase + m0 + mr + r) * COUT + col;
                float v = acc[i][j][r] + bs;
                yout[gi] = f2us(v);
                sloc[j] += v;
                qloc[j] += v * v;
            }
        }
    }

    for (int i = t; i < 128; i += TPB) red[i] = 0.f;
    __syncthreads();
#pragma unroll
    for (int j = 0; j < 4; j++) {
        float s = sloc[j], qv = qloc[j];
        s += __shfl_xor(s, 16); s += __shfl_xor(s, 32);
        qv += __shfl_xor(qv, 16); qv += __shfl_xor(qv, 32);
        if ((lane >> 4) == 0) {
            int cl = j * 16 + (lane & 15);
            atomicAdd(&red[cl], s);
            atomicAdd(&red[64 + cl], qv);
        }
    }
    __syncthreads();
    const int TILES = (N * HIN * WIN) >> 8;   // m-tiles per class
    const int PB = 4 * TILES;
    const int pb = cls * TILES + tile;
    for (int i = t; i < 64; i += TPB) {
        part[(size_t)(co0 + i) * PB + pb] = red[i];
        part[(size_t)(COUT + co0 + i) * PB + pb] = red[64 + i];
    }
}

// ---------------------------------------------------------------------------
// BN reduce / apply.
// ---------------------------------------------------------------------------
template<int C>
__global__ __launch_bounds__(64) void bn_reduce2(
    const float* __restrict__ part, float* __restrict__ st, int B)
{
    int i = blockIdx.x;
    int lane = threadIdx.x;
    float s = 0.f;
    for (int b = lane; b < B; b += 64) s += part[(size_t)i * B + b];
#pragma unroll
    for (int off = 1; off < 64; off <<= 1) s += __shfl_xor(s, off);
    if (lane == 0) st[i] = s;
}

template<int C>
__global__ __launch_bounds__(TPB) void bn_apply_v(
    unsigned short* __restrict__ x, const float* __restrict__ st,
    const float* __restrict__ g, const float* __restrict__ be, int M)
{
    __shared__ float sc[C], sh[C];
    int t = threadIdx.x;
    float cnt = (float)M;
    for (int c = t; c < C; c += TPB) {
        float m = st[c] / cnt;
        float v = st[C + c] / cnt - m * m;
        float s = g[c] * rsqrtf(v + 1e-5f);
        sc[c] = s;
        sh[c] = be[c] - m * s;
    }
    __syncthreads();
    constexpr int GPT = C / 8;
    size_t tot = (size_t)M * GPT;
    for (size_t slot = (size_t)blockIdx.x * TPB + t; slot < tot;
         slot += (size_t)gridDim.x * TPB) {
        int c0 = (int)(slot % GPT) * 8;
        int4 v = *(int4*)(x + slot * 8);
        unsigned int* vu = (unsigned int*)&v;
#pragma unroll
        for (int k = 0; k < 4; k++) {
            float f0 = fmaxf(us2f(vu[k] & 0xffffu) * sc[c0 + 2 * k] + sh[c0 + 2 * k], 0.f);
            float f1 = fmaxf(us2f(vu[k] >> 16) * sc[c0 + 2 * k + 1] + sh[c0 + 2 * k + 1], 0.f);
            vu[k] = (unsigned int)f2us(f0) | ((unsigned int)f2us(f1) << 16);
        }
        *(int4*)(x + slot * 8) = v;
    }
}

// ---------------------------------------------------------------------------
// VQ stage 1: codebook split hi/lo bf16 + cn2.
// ---------------------------------------------------------------------------
__global__ __launch_bounds__(TPB) void cb_prep(
    const float* __restrict__ cb, unsigned short* __restrict__ chb,
    unsigned short* __restrict__ clb, float* __restrict__ cn2)
{
    int j = blockIdx.x, d = threadIdx.x;
    float v = cb[j * 256 + d];
    unsigned short h = f2us(v);
    chb[j * 256 + d] = h;
    clb[j * 256 + d] = f2us(v - us2f(h));
    float s = v * v;
#pragma unroll
    for (int off = 1; off < 64; off <<= 1) s += __shfl_xor(s, off);
    __shared__ float p[4];
    if ((d & 63) == 0) p[d >> 6] = s;
    __syncthreads();
    if (d == 0) cn2[j] = p[0] + p[1] + p[2] + p[3];
}

// ---------------------------------------------------------------------------
// VQ stage 2: split-bf16 MFMA distance GEMM with fused per-wave argmin.
// ---------------------------------------------------------------------------
__global__ __launch_bounds__(TPB) void vq_gemm(
    const unsigned short* __restrict__ zh, const unsigned short* __restrict__ zl,
    const unsigned short* __restrict__ chb, const unsigned short* __restrict__ clb,
    const float* __restrict__ cn2, float* __restrict__ valp, int* __restrict__ idxp)
{
    __shared__ __align__(16) unsigned short Ah[2][8 * 512];
    __shared__ __align__(16) unsigned short Al[2][8 * 512];
    __shared__ __align__(16) unsigned short Bh[2][8 * 512];
    __shared__ __align__(16) unsigned short Bl[2][8 * 512];

    const int t = threadIdx.x, lane = t & 63, wave = t >> 6;
    const int wm = wave >> 1, wn = wave & 1;
    const int gdec = (int)blockIdx.x >> 3, xs = (int)blockIdx.x & 7;
    const int cbk = gdec & 1;
    const int m0 = (((gdec >> 1) << 3) + xs) * 128;
    const int co0 = cbk * 128;
    const int lr = lane & 15, lc = lane >> 4;

    size_t a0 = (size_t)(m0 + wave * 16 + lr) * 256 + lc * 8;
    size_t a1 = a0 + 64 * 256;
    size_t b0 = (size_t)(co0 + wave * 16 + lr) * 256 + lc * 8;
    size_t b1 = b0 + 64 * 256;

    v4f acc[4][4];
#pragma unroll
    for (int i = 0; i < 4; i++)
#pragma unroll
        for (int j = 0; j < 4; j++)
#pragma unroll
            for (int r = 0; r < 4; r++) acc[i][j][r] = 0.f;

    auto do_stage = [&](int ci0, int pb) {
        gl_lds16(zh + a0 + ci0, &Ah[pb][wave * 512]);
        gl_lds16(zh + a1 + ci0, &Ah[pb][(wave + 4) * 512]);
        gl_lds16(zl + a0 + ci0, &Al[pb][wave * 512]);
        gl_lds16(zl + a1 + ci0, &Al[pb][(wave + 4) * 512]);
        gl_lds16(chb + b0 + ci0, &Bh[pb][wave * 512]);
        gl_lds16(chb + b1 + ci0, &Bh[pb][(wave + 4) * 512]);
        gl_lds16(clb + b0 + ci0, &Bl[pb][wave * 512]);
        gl_lds16(clb + b1 + ci0, &Bl[pb][(wave + 4) * 512]);
    };

    do_stage(0, 0);
    __syncthreads();

    for (int s = 0; s < 8; ++s) {
        const int pb = s & 1;
        if (s < 7) do_stage((s + 1) * 32, pb ^ 1);

        v8s a_h[4], a_l[4], b_h[4], b_l[4];
#pragma unroll
        for (int i = 0; i < 4; i++) {
            a_h[i] = *(const v8s*)&Ah[pb][(wm * 4 + i) * 512 + lane * 8];
            a_l[i] = *(const v8s*)&Al[pb][(wm * 4 + i) * 512 + lane * 8];
        }
#pragma unroll
        for (int j = 0; j < 4; j++) {
            b_h[j] = *(const v8s*)&Bh[pb][(wn * 4 + j) * 512 + lane * 8];
            b_l[j] = *(const v8s*)&Bl[pb][(wn * 4 + j) * 512 + lane * 8];
        }
#pragma unroll
        for (int i = 0; i < 4; i++)
#pragma unroll
            for (int j = 0; j < 4; j++) {
                acc[i][j] = __builtin_amdgcn_mfma_f32_16x16x32_bf16(a_h[i], b_h[j], acc[i][j], 0, 0, 0);
                acc[i][j] = __builtin_amdgcn_mfma_f32_16x16x32_bf16(a_h[i], b_l[j], acc[i][j], 0, 0, 0);
                acc[i][j] = __builtin_amdgcn_mfma_f32_16x16x32_bf16(a_l[i], b_h[j], acc[i][j], 0, 0, 0);
            }
        __syncthreads();
    }

#pragma unroll
    for (int i = 0; i < 4; i++) {
#pragma unroll
        for (int r = 0; r < 4; r++) {
            float best = 3.4e38f;
            int bi = 0;
#pragma unroll
            for (int j = 0; j < 4; j++) {
                int col = co0 + wn * 64 + j * 16 + (lane & 15);
                float d = cn2[col] - 2.f * acc[i][j][r];
                if (d < best || (d == best && col < bi)) { best = d; bi = col; }
            }
#pragma unroll
            for (int off = 1; off < 16; off <<= 1) {
                float ov = __shfl_xor(best, off);
                int oi = __shfl_xor(bi, off);
                if (ov < best || (ov == best && oi < bi)) { best = ov; bi = oi; }
            }
            if ((lane & 15) == 0) {
                int row = m0 + wm * 64 + i * 16 + (lane >> 4) * 4 + r;
                valp[(size_t)row * 4 + cbk * 2 + wn] = best;
                idxp[(size_t)row * 4 + cbk * 2 + wn] = bi;
            }
        }
    }
}

// ---------------------------------------------------------------------------
// VQ stage 3+4 fused: per-row candidate combine + gather + loss.
// ---------------------------------------------------------------------------
__global__ __launch_bounds__(TPB) void vq_gather2(
    const unsigned short* __restrict__ zh, const unsigned short* __restrict__ zl,
    const float* __restrict__ cb, const float* __restrict__ valp,
    const int* __restrict__ idxp, unsigned short* __restrict__ hq,
    float* __restrict__ rowloss)
{
    int row = blockIdx.x * 4 + (threadIdx.x >> 6);
    int lane = threadIdx.x & 63;
    float best = valp[(size_t)row * 4];
    int j = idxp[(size_t)row * 4];
#pragma unroll
    for (int c = 1; c < 4; c++) {
        float v = valp[(size_t)row * 4 + c];
        if (v < best) { best = v; j = idxp[(size_t)row * 4 + c]; }
    }
    ushort4 hv = *(const ushort4*)(zh + (size_t)row * 256 + lane * 4);
    ushort4 lv = *(const ushort4*)(zl + (size_t)row * 256 + lane * 4);
    float4 cv = *(const float4*)(cb + (size_t)j * 256 + lane * 4);
    float z0 = us2f(hv.x) + us2f(lv.x);
    float z1 = us2f(hv.y) + us2f(lv.y);
    float z2 = us2f(hv.z) + us2f(lv.z);
    float z3 = us2f(hv.w) + us2f(lv.w);
    float d0 = z0 - cv.x, d1 = z1 - cv.y, d2 = z2 - cv.z, d3 = z3 - cv.w;
    float d = d0 * d0 + d1 * d1 + d2 * d2 + d3 * d3;
#pragma unroll
    for (int off = 1; off < 64; off <<= 1) d += __shfl_xor(d, off);
    if (lane == 0) rowloss[row] = d;
    ushort4 o;
    o.x = f2us(cv.x); o.y = f2us(cv.y); o.z = f2us(cv.z); o.w = f2us(cv.w);
    *(ushort4*)(hq + (size_t)row * 256 + lane * 4) = o;
}

// Single-kernel loss reduction.
__global__ __launch_bounds__(TPB) void loss_all(
    const float* __restrict__ rowloss, float* __restrict__ out2)
{
    int t = threadIdx.x;
    float v = 0.f;
    for (int i = t; i < 32768; i += TPB) v += rowloss[i];
#pragma unroll
    for (int off = 1; off < 64; off <<= 1) v += __shfl_xor(v, off);
    __shared__ float p[4];
    if ((t & 63) == 0) p[t >> 6] = v;
    __syncthreads();
    if (t == 0) {
        float m = (p[0] + p[1] + p[2] + p[3]) * (1.0f / 32768.0f);
        out2[0] = m;
        out2[1] = m;
    }
}

// ---------------------------------------------------------------------------
// Decoder L4: MFMA + FUSED BN(g3)+ReLU in the reg-staging.
// ---------------------------------------------------------------------------
__global__ __launch_bounds__(TPB) void conv_d4(
    const unsigned short* __restrict__ xb, const unsigned short* __restrict__ wrep,
    const float* __restrict__ st, const float* __restrict__ gg,
    const float* __restrict__ be, const float* __restrict__ bias,
    float* __restrict__ out, int N)
{
    __shared__ __align__(16) unsigned short xsm[8 * 409 * 8];   // 52.4 KB
    __shared__ float scs[64], shs[64];
    int4* xsI = (int4*)xsm;
    const int t = threadIdx.x;
    const int lane = t & 63, wave = t >> 6;
    const int lr = lane & 15, lc = lane >> 4;

    if (t < 64) {
        float cnt = (float)(N * 4096);
        float m = st[t] / cnt;
        float vv = st[64 + t] / cnt - m * m;
        float s = gg[t] * rsqrtf(vv + 1e-5f);
        scs[t] = s;
        shs[t] = be[t] - m * s;
    }
    __syncthreads();

    const int n = blockIdx.x >> 4;
    const int tile = blockIdx.x & 15;
    const int th = tile >> 2, tw = tile & 3;
    const int ihh0 = 8 * th - 1, iwh0 = 8 * tw - 1;

    for (int s = t; s < 3200; s += TPB) {
        int cls = s / 800;
        int rem = s % 800;
        int ihh_l = rem / 80;
        int i4 = rem % 80;
        int iwh_l = i4 >> 3, c8 = i4 & 7;
        int ihh_g = ihh0 + ihh_l;
        int iwh_g = iwh0 + iwh_l;
        int4 v;
        if ((unsigned)ihh_g < 32u && (unsigned)iwh_g < 32u) {
            size_t row = (((size_t)cls * 128 + n) * 32 + ihh_g) * 32 + iwh_g;
            v = *(const int4*)(xb + row * 64 + c8 * 8);
            unsigned int* vu = (unsigned int*)&v;
            int c0 = c8 * 8;
#pragma unroll
            for (int k = 0; k < 4; k++) {
                float f0 = fmaxf(us2f(vu[k] & 0xffffu) * scs[c0 + 2 * k] + shs[c0 + 2 * k], 0.f);
                float f1 = fmaxf(us2f(vu[k] >> 16) * scs[c0 + 2 * k + 1] + shs[c0 + 2 * k + 1], 0.f);
                vu[k] = (unsigned int)f2us(f0) | ((unsigned int)f2us(f1) << 16);
            }
        } else {
            v.x = v.y = v.z = v.w = 0;
        }
        xsI[c8 * 409 + cls * 102 + ihh_l * 10 + iwh_l] = v;
    }
    __syncthreads();

    int abase[4][9];
#pragma unroll
    for (int q = 0; q < 4; q++) {
        int seg = wave * 4 + q;
        int oh = th * 16 + seg;
        int ow = tw * 16 + lr;
#pragma unroll
        for (int tap = 0; tap < 9; tap++) {
            int kh = tap / 3, kw = tap % 3;
            int ih = oh - 1 + kh, iw = ow - 1 + kw;
            int clsi = ((ih & 1) << 1) | (iw & 1);
            abase[q][tap] = clsi * 102 + ((ih >> 1) - ihh0) * 10 + ((iw >> 1) - iwh0);
        }
    }

    v4f acc[4];
#pragma unroll
    for (int q = 0; q < 4; q++)
#pragma unroll
        for (int r = 0; r < 4; r++) acc[q][r] = 0.f;

#pragma unroll
    for (int kk = 0; kk < 18; kk++) {
        const int tap = kk >> 1, half = kk & 1;
        const int c8 = half * 4 + lc;
        v8s b = *(const v8s*)(wrep + kk * 512 + lane * 8);
#pragma unroll
        for (int q = 0; q < 4; q++) {
            v8s a = *(const v8s*)&xsI[c8 * 409 + abase[q][tap]];
            acc[q] = __builtin_amdgcn_mfma_f32_16x16x32_bf16(a, b, acc[q], 0, 0, 0);
        }
    }

    if (lr < 3) {
        float bs = bias[lr];
#pragma unroll
        for (int q = 0; q < 4; q++) {
            int seg = wave * 4 + q;
            int oh = th * 16 + seg;
            int ow0 = tw * 16 + lc * 4;
            float4 v;
            v.x = acc[q][0] + bs; v.y = acc[q][1] + bs;
            v.z = acc[q][2] + bs; v.w = acc[q][3] + bs;
            *(float4*)&out[((size_t)n * 3 + lr) * 4096 + oh * 64 + ow0] = v;
        }
    }
}

// ---------------------------------------------------------------------------

extern "C" void kernel_launch(void* const* d_in, const int* in_sizes, int n_in,
                              void* d_out, int out_size, void* d_ws, size_t ws_size,
                              hipStream_t stream) {
    const float* x    = (const float*)d_in[0];
    const float* cb   = (const float*)d_in[1];
    const float* e_w1 = (const float*)d_in[2];  const float* e_b1 = (const float*)d_in[3];
    const float* e_g1 = (const float*)d_in[4];  const float* e_be1 = (const float*)d_in[5];
    const float* e_w2 = (const float*)d_in[6];  const float* e_b2 = (const float*)d_in[7];
    const float* e_g2 = (const float*)d_in[8];  const float* e_be2 = (const float*)d_in[9];
    const float* e_w3 = (const float*)d_in[10]; const float* e_b3 = (const float*)d_in[11];
    const float* e_g3 = (const float*)d_in[12]; const float* e_be3 = (const float*)d_in[13];
    const float* e_w4 = (const float*)d_in[14]; const float* e_b4 = (const float*)d_in[15];
    const float* d_w1 = (const float*)d_in[16]; const float* d_b1 = (const float*)d_in[17];
    const float* d_g1 = (const float*)d_in[18]; const float* d_be1 = (const float*)d_in[19];
    const float* d_w2 = (const float*)d_in[20]; const float* d_b2 = (const float*)d_in[21];
    const float* d_g2 = (const float*)d_in[22]; const float* d_be2 = (const float*)d_in[23];
    const float* d_w3 = (const float*)d_in[24]; const float* d_b3 = (const float*)d_in[25];
    const float* d_g3 = (const float*)d_in[26]; const float* d_be3 = (const float*)d_in[27];
    const float* d_w4 = (const float*)d_in[28]; const float* d_b4 = (const float*)d_in[29];

    float* ws = (float*)d_ws;
    unsigned short* h1 = (unsigned short*)(ws);              // class-major after E1
    unsigned short* g3 = h1;                                 // class-major after D3 (pre-BN)
    unsigned short* h2 = (unsigned short*)(ws + 16777216);   // [.., 25165824)
    unsigned short* g2 = h2;                                 // class-major after D2
    unsigned short* h3 = (unsigned short*)(ws + 25165824);   // [.., 28311552)
    unsigned short* g1 = h3;
    unsigned short* zh = (unsigned short*)(ws + 28311552);   // 8.4M shorts
    unsigned short* zl = (unsigned short*)(ws + 32505856);   // 8.4M shorts
    unsigned short* hq = (unsigned short*)(ws + 36700160);   // [.., 40894464)
    float* stats = ws + 40960000;                            // 3072
    unsigned short* we1 = (unsigned short*)(ws + 40963072);  // 2048 shorts
    unsigned short* wd4r = (unsigned short*)(ws + 40964096); // 9216 shorts
    float* cn2 = ws + 40995904;                              // 256
    unsigned short* chb = (unsigned short*)(ws + 40996160);  // 65536 shorts
    unsigned short* clb = (unsigned short*)(ws + 41028928);  // 65536 shorts
    unsigned short* wrep = (unsigned short*)(ws + 41061696);
    unsigned short* we2 = wrep + 0;        // 16*128*64   = 131072 (fragment-major)
    unsigned short* we3 = wrep + 131072;   // 16*192*128  = 393216
    unsigned short* we4 = wrep + 524288;   // 256*192     = 49152
    unsigned short* wd1 = wrep + 573440;   // 192*256     = 49152
    unsigned short* wd2 = wrep + 622592;   // 4*4*128*192 = 393216
    unsigned short* wd3 = wrep + 1015808;  // 4*4*64*128  = 131072
    float* part = ws + 41635136;           // BN partials / VQ candidates (8.4M floats)
    float* valp = part;                    // 131072 floats (dead outside VQ window)
    int* idxp = (int*)(part + 131072);     // 131072 ints
    float* rowloss = ws + 50023744;                          // 32768
    unsigned short* zpage = (unsigned short*)(ws + 50122112); // 512 B of zeros
    float* out = (float*)d_out;
    float* losses = out + 1572864;

    const int N = 128;

    // ---- all weight repacks + codebook prep (2 launches total) ----
    repack_all<<<4525, TPB, 0, stream>>>(
        e_w1, d_w4, e_w2, e_w3, e_w4, d_w1, d_w2, d_w3,
        we1, wd4r, we2, we3, we4, wd1, wd2, wd3, zpage);
    cb_prep<<<256, TPB, 0, stream>>>(cb, chb, clb, cn2);

    // ---- E1: 3->64 k3 s1 p1, FUSED im2col+MFMA GEMM -> CLASS-MAJOR h1 ----
    e1_gemm<<<4096, TPB, 0, stream>>>(x, we1, e_b1, h1, part, N);
    bn_reduce2<64><<<128, 64, 0, stream>>>(part, stats + 0 * 512, 4096);
    bn_apply_v<64><<<4096, TPB, 0, stream>>>(h1, stats + 0 * 512, e_g1, e_be1, 524288);

    // ---- E2: 64->128 k4 s2 p1, class-major input, contiguous DMA ----
    conv_c<64, 128, 32, 32, 2>
        <<<1024, TPB, 0, stream>>>(h1, we2, e_b2, h2, part, zpage, N);
    bn_reduce2<128><<<256, 64, 0, stream>>>(part, stats + 1 * 512, 512);
    bn_apply_v<128><<<2048, TPB, 0, stream>>>(h2, stats + 1 * 512, e_g2, e_be2, 131072);

    // ---- E3: 128->192 k4 s2 p1 (MFMA BK=64, dbuf, fused stats, XCD-aware) ----
    conv_mfma<128, 192, 32, 32, 4, 2, 1, 96, 0, 2>
        <<<512, TPB, 0, stream>>>(h2, we3, e_b3, h3, nullptr, part, zpage, N);
    bn_reduce2<192><<<384, 64, 0, stream>>>(part, stats + 2 * 512, 256);
    bn_apply_v<192><<<1024, TPB, 0, stream>>>(h3, stats + 2 * 512, e_g3, e_be3, 32768);

    // ---- E4: 192->256 1x1 (MFMA BK=64, dbuf, hi/lo split out for VQ) ----
    conv_mfma<192, 256, 16, 16, 1, 1, 0, 128, 2, 2>
        <<<512, TPB, 0, stream>>>(h3, we4, e_b4, zh, zl, nullptr, zpage, N);

    // ---- VQ: fused GEMM+argmin -> gather(with combine) -> loss ----
    vq_gemm<<<512, TPB, 0, stream>>>(zh, zl, chb, clb, cn2, valp, idxp);
    vq_gather2<<<8192, TPB, 0, stream>>>(zh, zl, cb, valp, idxp, hq, rowloss);
    loss_all<<<1, TPB, 0, stream>>>(rowloss, losses);

    // ---- D1: 256->192 1x1 convT (MFMA BK=64, dbuf, fused stats, XCD-aware) ----
    conv_mfma<256, 192, 16, 16, 1, 1, 0, 96, 0, 2>
        <<<512, TPB, 0, stream>>>(hq, wd1, d_b1, g1, nullptr, part, zpage, N);
    bn_reduce2<192><<<384, 64, 0, stream>>>(part, stats + 3 * 512, 256);
    bn_apply_v<192><<<1024, TPB, 0, stream>>>(g1, stats + 3 * 512, d_g1, d_be1, 32768);

    // ---- D2: 192->128 convT, barrier-free dbuf + hoisted addrs (v4) ----
    convt_nb<192, 128, 16, 16, 2, 0>
        <<<1024, TPB, 0, stream>>>(g1, wd2, d_b2, g2, part, zpage, N);
    bn_reduce2<128><<<256, 64, 0, stream>>>(part, stats + 4 * 512, 512);
    bn_apply_v<128><<<2048, TPB, 0, stream>>>(g2, stats + 4 * 512, d_g2, d_be2, 131072);

    // ---- D3: 128->64 convT, barrier-free dbuf + hoisted addrs (v4) ----
    convt_nb<128, 64, 32, 32, 1, 1>
        <<<2048, TPB, 0, stream>>>(g2, wd3, d_b3, g3, part, zpage, N);
    bn_reduce2<64><<<128, 64, 0, stream>>>(part, stats + 5 * 512, 2048);
    // bn_apply for g3 FUSED into conv_d4 staging (sole consumer).

    // ---- D4: 64->3 k3 s1 p1 (MFMA, fused BN+ReLU staging) -> NCHW fp32 ----
    conv_d4<<<2048, TPB, 0, stream>>>(g3, wd4r, stats + 5 * 512, d_g3, d_be3,
                                      d_b4, out, N);
}